// Round 3
// baseline (512.057 us; speedup 1.0000x reference)
//
#include <hip/hip_runtime.h>
#include <hip/hip_fp16.h>

// B=256 queries, D=2048, d=64 hash dim, N=100000 database, C=100 classes,
// K=1000 SMALLEST-sim selection. Inputs f32, labels int, output f32.
//
// R9: fused cooperative kernel (512 blocks x 256 thr), SINGLE graph node (no
// memset — R7-proven shape). Custom grid barrier, init-free & poison-proof:
//   arrivals: 64-bit CAS-tag-install-or-add words (8 shards @128B + root),
//             fire on count % N == 0 (monotonic across iterations);
//   release:  sense-free — spinner snapshots its flag word BEFORE arriving,
//             RMW-polls (atomicAdd+0, coherence-point-forced) until changed;
//             releaser bumps all 64 flag lines (+1).
//   fences:   __threadfence() by ALL threads at entry (wbl2: publish plain
//             stores cross-XCD) and exit (inv: fresh reads) — the proven
//             threadfence-reduction idiom. No __hip_atomic_*, no atomic-load
//             spins (R8's suspected hang).
// Phases: P0 prep(cvt+out+detect) | P1 mhist | P2 scan | P3 mclass | P4 final.
//
// Math identical to R6/R7 (MFMA f16 screen with rigorous error bound M,
// bucket histogram -> threshold bucket -> certain-below / certain-out /
// candidate window, exact f64 resolve of ~265 candidates/row).

#define NBK 256          // buckets per row histogram (pow2)
#define CAPC 1024        // per-row candidate capacity at final (expected ~265)
#define CAPB 64          // per-(chunk,row) segment capacity (expected ~4)
#define MROWS 32         // out-rows per MFMA block (two 16-row tiles)
#define NCHX 64          // code-chunks for MFMA passes
#define NCLS 100
#define MTAG 0x0B57AC1EULL            // arrival-word tag (high 32 bits)
#define GBS  (80 * 16)                // ull per barrier (80 slots x 128B)

typedef _Float16 half8 __attribute__((ext_vector_type(8)));
typedef float floatx4 __attribute__((ext_vector_type(4)));

struct KArgs {
  const float* x; const float* W; const float* codes; const int* labels; const int* Kp;
  double* out64; float2* rowTH; unsigned short* out16; double* B1sq;
  int* shiftp; float* cmaxSlab; unsigned* belowCnt; unsigned* ccnt; unsigned* cand;
  unsigned short* histg; unsigned short* codes16; unsigned long long* gbar; float* outp;
  int N, Npad, cpb, B, D, nCvt;
};

static __device__ __forceinline__ unsigned packh2(float a, float b) {
  _Float16 ha = (_Float16)a, hb = (_Float16)b;      // RNE
  unsigned short ua, ub;
  __builtin_memcpy(&ua, &ha, 2); __builtin_memcpy(&ub, &hb, 2);
  return (unsigned)ua | ((unsigned)ub << 16);
}

// shared range math (1-ulp discrepancies absorbed by 2M margins, M>=0.05)
static __device__ __forceinline__ void rowRange(double b1sq, double cmax,
                                                double& lo, double& inv, double& bw) {
  double hr = 0.5 * sqrt(b1sq * cmax) * 1.000001 + 9.0;  // +9 >> M
  lo = 50.0 - hr;
  bw = (2.0 * hr) / (double)NBK;
  inv = (double)NBK / (2.0 * hr);
}

// exact f64 dot for candidate resolution (order-stable chain)
static __device__ __forceinline__ double dot1(const float* __restrict__ codes, int n,
                                              const double* __restrict__ od) {
  const float4* crow = (const float4*)(codes + (size_t)n * 64);
  double a = 0.0;
#pragma unroll
  for (int i = 0; i < 16; ++i) {
    float4 q = crow[i];
    a = fma((double)q.x, od[i*4+0], a);
    a = fma((double)q.y, od[i*4+1], a);
    a = fma((double)q.z, od[i*4+2], a);
    a = fma((double)q.w, od[i*4+3], a);
  }
  return a;
}

// ---- MFMA A-fragment loader (mfma_f32_16x16x32_f16 layout, m89-verified):
//   A: lane holds A[m = lane&15][k = (lane>>4)*8 + j]; D: reg r = D[(lane>>4)*4+r][lane&15]
static __device__ __forceinline__ void loadA(const unsigned short* __restrict__ out16,
                                             int m0, int mr, int quad,
                                             half8& a00, half8& a01, half8& a10, half8& a11) {
  const uint4* o4 = (const uint4*)out16;
  uint4 u;
  u = o4[(size_t)(m0 + mr) * 8 + quad];          __builtin_memcpy(&a00, &u, 16);
  u = o4[(size_t)(m0 + mr) * 8 + 4 + quad];      __builtin_memcpy(&a01, &u, 16);
  u = o4[(size_t)(m0 + 16 + mr) * 8 + quad];     __builtin_memcpy(&a10, &u, 16);
  u = o4[(size_t)(m0 + 16 + mr) * 8 + 4 + quad]; __builtin_memcpy(&a11, &u, 16);
}

// ---- arrival word: CAS-install tag from arbitrary (poisoned) state, else
// fetch_add. Returns the new count (low 32 bits). Counts are monotonic
// across iterations; callers test count % N == 0.
static __device__ unsigned arrive64(unsigned long long* w) {
  unsigned long long v = atomicAdd(w, 0ULL);           // RMW read (coherent)
  while ((v >> 32) != MTAG) {
    unsigned long long old = atomicCAS(w, v, (MTAG << 32) | 1ULL);
    if (old == v) return 1u;                           // installed; count = 1
    v = old;                                           // someone else won; retry
  }
  return (unsigned)(atomicAdd(w, 1ULL) & 0xFFFFFFFFULL) + 1u;
}

// ---- init-free grid barrier. Slots (128B apart): 0..7 shard, 8 root,
// 9..72 per-block-group flags. Spinner snapshots flag BEFORE arriving; spins
// (RMW-poll) until it changes; releaser bumps all 64 flags.
static __device__ __forceinline__ void gridBar(unsigned long long* st, int nblk,
                                               int* srel) {
  __threadfence();                         // publish this block's plain stores
  __syncthreads();
  unsigned long long pre = 0;
  unsigned long long* f = st + (size_t)(9 + ((int)blockIdx.x & 63)) * 16;
  if (threadIdx.x == 0) {
    pre = atomicAdd(f, 0ULL);              // snapshot BEFORE arrival
    int sh = (int)blockIdx.x & 7;
    unsigned shardN = (unsigned)((nblk - sh + 7) >> 3);
    unsigned c = arrive64(st + (size_t)sh * 16);
    int rel = 0;
    if (c % shardN == 0u) rel = (arrive64(st + 8 * 16) % 8u == 0u);
    *srel = rel;
  }
  __syncthreads();
  if (*srel) {                             // releaser block: bump all 64 flags
    if (threadIdx.x < 64)
      atomicAdd(st + (size_t)(9 + threadIdx.x) * 16, 1ULL);
  } else if (threadIdx.x == 0) {
    while (atomicAdd(f, 0ULL) == pre) __builtin_amdgcn_s_sleep(8);
  }
  __syncthreads();
  __threadfence();                         // invalidate: fresh cross-XCD reads
}

// deterministic block-level max over the cvtnorm slab (bit-identical wherever called)
static __device__ __forceinline__ float reduceCmax(const float* __restrict__ slab,
                                                   int n, float* fred) {
  int tid = (int)threadIdx.x;
  float m = 0.0f;
  for (int i = tid; i < n; i += 256) m = fmaxf(m, slab[i]);
  fred[tid] = m; __syncthreads();
  for (int off = 128; off > 0; off >>= 1) {
    if (tid < off) fred[tid] = fmaxf(fred[tid], fred[tid + off]);
    __syncthreads();
  }
  float r = fred[0];
  __syncthreads();
  return r;
}

struct SMemP0 { double red[256]; float fred[256]; int flag; };
struct SMemP1 { unsigned hist[MROWS * NBK]; float sP[MROWS]; float sQ[MROWS]; float fred[256]; };
struct SMemP2 { unsigned s[NBK]; float fred[256]; };
struct SMemP3 { unsigned lab[MROWS * NCLS]; unsigned lcnt[MROWS]; float sTL[MROWS]; float sTH[MROWS]; };
struct SMemP4 { double key[CAPC]; int kidx[CAPC]; unsigned lab[NCLS]; int soff[NCHX + 1]; unsigned btot; };
union SMem { SMemP0 p0; SMemP1 p1; SMemP2 p2; SMemP3 p3; SMemP4 p4; };  // max ~33.3 KB

__global__ __launch_bounds__(256, 2) void k_fused(KArgs A) {
  __shared__ SMem sm;
  __shared__ int s_rel;
  const int tid = (int)threadIdx.x;
  const int blk = (int)blockIdx.x;
  const int nblk = (int)gridDim.x;
  const int B = A.B, N = A.N, Npad = A.Npad, cpb = A.cpb, D = A.D;

  // =============== P0: cvtnorm (blk<nCvt) + out (last B blocks) + detect ===============
  if (blk < A.nCvt) {            // codes f32 -> f16 (RNE) + per-block max ||code||^2
    int n = blk * 256 + tid;
    float m = 0.0f;
    if (n < N) {
      const float4* crow = (const float4*)(A.codes + (size_t)n * 64);
      uint4* orow = (uint4*)(A.codes16 + (size_t)n * 64);
      double c2 = 0.0;
#pragma unroll
      for (int i = 0; i < 8; ++i) {
        float4 qa = crow[2*i], qb = crow[2*i+1];
        c2 = fma((double)qa.x, (double)qa.x, c2); c2 = fma((double)qa.y, (double)qa.y, c2);
        c2 = fma((double)qa.z, (double)qa.z, c2); c2 = fma((double)qa.w, (double)qa.w, c2);
        c2 = fma((double)qb.x, (double)qb.x, c2); c2 = fma((double)qb.y, (double)qb.y, c2);
        c2 = fma((double)qb.z, (double)qb.z, c2); c2 = fma((double)qb.w, (double)qb.w, c2);
        uint4 o;
        o.x = packh2(qa.x, qa.y); o.y = packh2(qa.z, qa.w);
        o.z = packh2(qb.x, qb.y); o.w = packh2(qb.z, qb.w);
        orow[i] = o;
      }
      m = (float)(c2 * 1.000001);
    } else {                     // n < Npad always here
      uint4* orow = (uint4*)(A.codes16 + (size_t)n * 64);
      uint4 z = {0u, 0u, 0u, 0u};
#pragma unroll
      for (int i = 0; i < 8; ++i) orow[i] = z;
    }
    sm.p0.fred[tid] = m; __syncthreads();
    for (int off = 128; off > 0; off >>= 1) {
      if (tid < off) sm.p0.fred[tid] = fmaxf(sm.p0.fred[tid], sm.p0.fred[tid + off]);
      __syncthreads();
    }
    if (tid == 0) A.cmaxSlab[blk] = sm.p0.fred[0];     // plain store (no init needed)
    __syncthreads();
  }
  if (blk >= nblk - B) {         // out = x @ W in f64 (+f16 copy), ||out_b||^2
    int b = blk - (nblk - B);
    int t = tid & 63, w = tid >> 6;    // w in 0..3
    int kc = D >> 2;                   // 512 for D=2048
    int k0 = w * kc;
    const float* xr = A.x + (size_t)b * D;
    double a[8];
#pragma unroll
    for (int j = 0; j < 8; ++j) a[j] = 0.0;
    for (int k = k0; k < k0 + kc; k += 8) {
      float4 xv0 = *(const float4*)(xr + k);
      float4 xv1 = *(const float4*)(xr + k + 4);
      float xs[8] = {xv0.x, xv0.y, xv0.z, xv0.w, xv1.x, xv1.y, xv1.z, xv1.w};
#pragma unroll
      for (int j = 0; j < 8; ++j)
        a[j] = fma((double)xs[j], (double)A.W[(size_t)(k + j) * 64 + t], a[j]);
    }
    __syncthreads();
    sm.p0.red[tid] = ((a[0] + a[1]) + (a[2] + a[3])) + ((a[4] + a[5]) + (a[6] + a[7]));
    __syncthreads();
    if (w == 0) {
      double o = 0.0;
#pragma unroll
      for (int j = 0; j < 4; ++j) o += sm.p0.red[t + 64 * j];
      A.out64[(size_t)b * 64 + t] = o;
      _Float16 h = (_Float16)(float)o;       // RNE
      unsigned short us; __builtin_memcpy(&us, &h, 2);
      A.out16[(size_t)b * 64 + t] = us;
      sm.p0.red[t] = o * o;                  // same-wave lanes: lockstep-safe
    }
    __syncthreads();
    if (tid == 0) {
      double s = 0.0;
      for (int i = 0; i < 64; ++i) s += sm.p0.red[i];
      A.B1sq[b] = s;
    }
  }
  if (blk == nblk - 1) {               // labels layout: int64 pairs vs int32
    if (tid == 0) sm.p0.flag = 0;
    __syncthreads();
    int m = N < 256 ? N : 256;
    if (tid < m && A.labels[2 * tid + 1] != 0) atomicOr(&sm.p0.flag, 1);
    __syncthreads();
    if (tid == 0) *A.shiftp = sm.p0.flag ? 0 : 1;      // label(n)=labels[n<<shift]
  }
  gridBar(A.gbar + 0 * GBS, nblk, &s_rel);

  // =============== P1: MFMA screen -> per-(chunk,row) u16 histogram slab ===============
  {
    int cx = blk & (NCHX - 1), y = blk >> 6;
    int m0 = y * MROWS;
    float cmax = reduceCmax(A.cmaxSlab, A.nCvt, sm.p1.fred);
    if (cx == 0) {                     // zero this y-group's belowCnt rows (pre-P3)
      for (int i = tid; i < MROWS * NCLS; i += 256) A.belowCnt[m0 * NCLS + i] = 0u;
    }
    for (int i = tid; i < MROWS * NBK; i += 256) sm.p1.hist[i] = 0u;
    if (tid < MROWS) {
      double lo, inv, bw;
      rowRange(A.B1sq[m0 + tid], (double)cmax, lo, inv, bw);
      sm.p1.sP[tid] = (float)(-0.5 * inv);   // bucket = trunc(d*P + Q), monotone in v
      sm.p1.sQ[tid] = (float)((50.0 - lo) * inv);
    }
    __syncthreads();
    int l = tid & 63, w = tid >> 6;
    int quad = l >> 4, mr = l & 15;
    half8 a00, a01, a10, a11;
    loadA(A.out16, m0, mr, quad, a00, a01, a10, a11);
    float P0[4], Q0[4], P1[4], Q1[4];
#pragma unroll
    for (int r = 0; r < 4; ++r) {
      P0[r] = sm.p1.sP[quad*4 + r];      Q0[r] = sm.p1.sQ[quad*4 + r];
      P1[r] = sm.p1.sP[16 + quad*4 + r]; Q1[r] = sm.p1.sQ[16 + quad*4 + r];
    }
    int cstart = cx * cpb;
    int cend = cstart + cpb; if (cend > N) cend = N;
    const uint4* c4 = (const uint4*)A.codes16;
    floatx4 z = {0.f, 0.f, 0.f, 0.f};
    for (int base = cstart; base < cend; base += 64) {
      int nrow = base + w * 16 + mr;
      int nc = nrow < Npad ? nrow : Npad - 1;
      uint4 ub0 = c4[(size_t)nc * 8 + quad];
      uint4 ub1 = c4[(size_t)nc * 8 + 4 + quad];
      half8 b0, b1;
      __builtin_memcpy(&b0, &ub0, 16); __builtin_memcpy(&b1, &ub1, 16);
      floatx4 d0 = __builtin_amdgcn_mfma_f32_16x16x32_f16(a00, b0, z, 0, 0, 0);
      d0 = __builtin_amdgcn_mfma_f32_16x16x32_f16(a01, b1, d0, 0, 0, 0);
      floatx4 d1 = __builtin_amdgcn_mfma_f32_16x16x32_f16(a10, b0, z, 0, 0, 0);
      d1 = __builtin_amdgcn_mfma_f32_16x16x32_f16(a11, b1, d1, 0, 0, 0);
      if (nrow < N) {
#pragma unroll
        for (int r = 0; r < 4; ++r) {
          int bk0 = (int)fmaf(d0[r], P0[r], Q0[r]);
          bk0 = bk0 < 0 ? 0 : (bk0 > NBK-1 ? NBK-1 : bk0);
          atomicAdd(&sm.p1.hist[(quad*4 + r) * NBK + bk0], 1u);   // LDS: local, fast
          int bk1 = (int)fmaf(d1[r], P1[r], Q1[r]);
          bk1 = bk1 < 0 ? 0 : (bk1 > NBK-1 ? NBK-1 : bk1);
          atomicAdd(&sm.p1.hist[(16 + quad*4 + r) * NBK + bk1], 1u);
        }
      }
    }
    __syncthreads();
    // exclusive slab, plain coalesced u16 stores (counts <= cpb=1600 < 65535)
    for (int i = tid; i < MROWS * NBK; i += 256)
      A.histg[((size_t)cx * B + (m0 + (i >> 8))) * NBK + (i & (NBK - 1))] =
          (unsigned short)sm.p1.hist[i];
  }
  gridBar(A.gbar + 1 * GBS, nblk, &s_rel);

  // =============== P2: per-row scan -> threshold bucket -> [TL,TH] ===============
  if (blk < B) {
    int b = blk;
    float cmaxf = reduceCmax(A.cmaxSlab, A.nCvt, sm.p2.fred);  // bit-identical to P1's
    unsigned acc = 0;
    for (int cx = 0; cx < NCHX; ++cx)
      acc += (unsigned)A.histg[((size_t)cx * B + b) * NBK + tid];   // coalesced u16
    sm.p2.s[tid] = acc;
    __syncthreads();
    for (int off = 1; off < NBK; off <<= 1) {
      unsigned add = (tid >= off) ? sm.p2.s[tid - off] : 0u;
      __syncthreads();
      sm.p2.s[tid] += add;
      __syncthreads();
    }
    unsigned K = (unsigned)A.Kp[0];
    unsigned cum = sm.p2.s[tid], prev = tid ? sm.p2.s[tid - 1] : 0u;
    if (cum >= K && prev < K) {          // exactly one thread: tb = tid
      double lo, inv, bw;
      double cmax = (double)cmaxf;
      rowRange(A.B1sq[b], cmax, lo, inv, bw);
      double S = sqrt(A.B1sq[b] * cmax);
      double M = 0.5 * S * 1.1e-3 + 0.05;    // f16 cvt + f32 accum bound
      double lot = lo + (double)tid * bw;
      A.rowTH[b] = make_float2((float)(lot - 2.0 * M - 1e-3),
                               (float)(lot + bw + 2.0 * M + 1e-3));
    }
  }
  gridBar(A.gbar + 2 * GBS, nblk, &s_rel);

  // =============== P3: MFMA recompute -> below label-hist / candidate segments ===============
  {
    int cx = blk & (NCHX - 1), y = blk >> 6;
    int m0 = y * MROWS;
    for (int i = tid; i < MROWS * NCLS; i += 256) sm.p3.lab[i] = 0u;
    if (tid < MROWS) {
      sm.p3.lcnt[tid] = 0u;
      float2 th = A.rowTH[m0 + tid];
      sm.p3.sTL[tid] = th.x; sm.p3.sTH[tid] = th.y;
    }
    __syncthreads();
    int l = tid & 63, w = tid >> 6;
    int quad = l >> 4, mr = l & 15;
    half8 a00, a01, a10, a11;
    loadA(A.out16, m0, mr, quad, a00, a01, a10, a11);
    float TL0[4], TH0[4], TL1[4], TH1[4];
#pragma unroll
    for (int r = 0; r < 4; ++r) {
      TL0[r] = sm.p3.sTL[quad*4 + r];      TH0[r] = sm.p3.sTH[quad*4 + r];
      TL1[r] = sm.p3.sTL[16 + quad*4 + r]; TH1[r] = sm.p3.sTH[16 + quad*4 + r];
    }
    int shift = *A.shiftp;
    int cstart = cx * cpb;
    int cend = cstart + cpb; if (cend > N) cend = N;
    const uint4* c4 = (const uint4*)A.codes16;
    floatx4 z = {0.f, 0.f, 0.f, 0.f};
    for (int base = cstart; base < cend; base += 64) {
      int nrow = base + w * 16 + mr;
      int nc = nrow < Npad ? nrow : Npad - 1;
      uint4 ub0 = c4[(size_t)nc * 8 + quad];
      uint4 ub1 = c4[(size_t)nc * 8 + 4 + quad];
      half8 b0, b1;
      __builtin_memcpy(&b0, &ub0, 16); __builtin_memcpy(&b1, &ub1, 16);
      int nl = nrow < N ? nrow : N - 1;
      int lv = A.labels[(size_t)nl << shift];
      floatx4 d0 = __builtin_amdgcn_mfma_f32_16x16x32_f16(a00, b0, z, 0, 0, 0);
      d0 = __builtin_amdgcn_mfma_f32_16x16x32_f16(a01, b1, d0, 0, 0, 0);
      floatx4 d1 = __builtin_amdgcn_mfma_f32_16x16x32_f16(a10, b0, z, 0, 0, 0);
      d1 = __builtin_amdgcn_mfma_f32_16x16x32_f16(a11, b1, d1, 0, 0, 0);
      if (nrow < N) {
#pragma unroll
        for (int r = 0; r < 4; ++r) {
          int rl0 = quad*4 + r, rl1 = 16 + quad*4 + r;
          float v0 = fmaf(d0[r], -0.5f, 50.0f);
          if (v0 < TL0[r]) {
            atomicAdd(&sm.p3.lab[rl0 * NCLS + lv], 1u);            // LDS
          } else if (v0 <= TH0[r]) {
            unsigned pos = atomicAdd(&sm.p3.lcnt[rl0], 1u);        // LDS, local
            if (pos < CAPB)
              A.cand[((size_t)cx * B + (m0 + rl0)) * CAPB + pos] = (unsigned)nrow;
          }
          float v1 = fmaf(d1[r], -0.5f, 50.0f);
          if (v1 < TL1[r]) {
            atomicAdd(&sm.p3.lab[rl1 * NCLS + lv], 1u);
          } else if (v1 <= TH1[r]) {
            unsigned pos = atomicAdd(&sm.p3.lcnt[rl1], 1u);
            if (pos < CAPB)
              A.cand[((size_t)cx * B + (m0 + rl1)) * CAPB + pos] = (unsigned)nrow;
          }
        }
      }
    }
    __syncthreads();
    if (tid < MROWS) {
      unsigned c = sm.p3.lcnt[tid];
      A.ccnt[(size_t)cx * B + (m0 + tid)] = c < CAPB ? c : CAPB;   // plain store
    }
    // below-class merge: fire-and-forget atomics (no return -> no wave stall)
    for (int i = tid; i < MROWS * NCLS; i += 256) {
      unsigned c = sm.p3.lab[i];
      if (c) atomicAdd(&A.belowCnt[(m0 + i / NCLS) * NCLS + i % NCLS], c);
    }
  }
  gridBar(A.gbar + 3 * GBS, nblk, &s_rel);

  // =============== P4: gather segments, exact f64 resolve, emit probs ===============
  if (blk < B) {
    int b = blk;
    if (tid == 0) sm.p4.btot = 0u;
    if (tid < NCHX) sm.p4.soff[tid + 1] = (int)A.ccnt[(size_t)tid * B + b];
    __syncthreads();
    if (tid == 0) {
      sm.p4.soff[0] = 0;
      for (int s = 0; s < NCHX; ++s) {
        int nx = sm.p4.soff[s] + sm.p4.soff[s + 1];
        sm.p4.soff[s + 1] = nx < CAPC ? nx : CAPC;
      }
    }
    for (int c = tid; c < NCLS; c += 256) {
      unsigned v = A.belowCnt[b * NCLS + c];
      if (v) atomicAdd(&sm.p4.btot, v);
    }
    __syncthreads();
    int cnt = sm.p4.soff[NCHX];
    for (int s = tid; s < NCHX; s += 256) {      // gather: ~4 entries/segment
      int c0 = sm.p4.soff[s], c1 = sm.p4.soff[s + 1];
      const unsigned* seg = A.cand + ((size_t)s * B + b) * CAPB;
      for (int j = 0; j < c1 - c0; ++j) sm.p4.kidx[c0 + j] = (int)seg[j];
    }
    __syncthreads();
    int K = A.Kp[0];
    int need = K - (int)sm.p4.btot;
    int M = 1; while (M < cnt) M <<= 1;
    const double* od = A.out64 + (size_t)b * 64;
    for (int i = tid; i < M; i += 256) {
      if (i < cnt) {
        sm.p4.key[i] = fma(dot1(A.codes, sm.p4.kidx[i], od), -0.5, 50.0);
      } else { sm.p4.key[i] = __builtin_inf(); sm.p4.kidx[i] = 0x7FFFFFFF; }
    }
    __syncthreads();
    for (int size = 2; size <= M; size <<= 1) {
      for (int stride = size >> 1; stride > 0; stride >>= 1) {
        for (int i = tid; i < M; i += 256) {
          int j = i ^ stride;
          if (j > i) {
            double ki = sm.p4.key[i], kj = sm.p4.key[j];
            int ii = sm.p4.kidx[i], ij = sm.p4.kidx[j];
            bool up = ((i & size) == 0);
            bool sw = up ? (kj < ki || (kj == ki && ij < ii))
                         : (kj > ki || (kj == ki && ij > ii));
            if (sw) { sm.p4.key[i] = kj; sm.p4.key[j] = ki;
                      sm.p4.kidx[i] = ij; sm.p4.kidx[j] = ii; }
          }
        }
        __syncthreads();
      }
    }
    for (int i = tid; i < NCLS; i += 256) sm.p4.lab[i] = 0u;
    __syncthreads();
    int shift = *A.shiftp;
    int take = need < cnt ? need : cnt;
    if (take < 0) take = 0;
    for (int i = tid; i < take; i += 256)
      atomicAdd(&sm.p4.lab[A.labels[(size_t)sm.p4.kidx[i] << shift]], 1u);
    __syncthreads();
    double Kd = (double)K;
    for (int c = tid; c < NCLS; c += 256)
      A.outp[b * NCLS + c] = (float)((double)(A.belowCnt[b * NCLS + c] + sm.p4.lab[c]) / Kd);
  }
}

extern "C" void kernel_launch(void* const* d_in, const int* in_sizes, int n_in,
                              void* d_out, int out_size, void* d_ws, size_t ws_size,
                              hipStream_t stream) {
  const float* x     = (const float*)d_in[0];
  const float* W     = (const float*)d_in[1];
  const float* codes = (const float*)d_in[2];
  const int* labels  = (const int*)d_in[3];
  const int* Kp      = (const int*)d_in[4];

  const int B = out_size / NCLS;             // 256
  const int N = in_sizes[3];                 // 100000
  const int D = in_sizes[0] / B;             // 2048
  const int Npad = (N + 255) & ~255;         // 100096
  const int cpb = (((N + NCHX - 1) / NCHX) + 63) & ~63;  // 1600 codes per chunk
  const int nCvt = Npad / 256;               // 391 cvtnorm blocks

  // ws layout; NOTHING needs host-side init (barrier is init-free/poison-proof).
  char* p = (char*)d_ws;
  unsigned long long* gbar = (unsigned long long*)p; p += (size_t)4 * GBS * 8;   // 40 KB
  double* out64      = (double*)p;   p += (size_t)B * 64 * sizeof(double);       // 128 KB
  float2* rowTH      = (float2*)p;   p += (size_t)B * sizeof(float2);            // 2 KB
  unsigned short* out16 = (unsigned short*)p; p += (size_t)B * 64 * 2;           // 32 KB
  double* B1sq       = (double*)p;   p += (size_t)B * sizeof(double);            // 2 KB
  int* shiftp        = (int*)p;      p += 64;
  float* cmaxSlab    = (float*)p;    p += 4096;                                  // nCvt floats
  unsigned* belowCnt = (unsigned*)p; p += (size_t)B * NCLS * sizeof(unsigned);   // 100 KB
  unsigned* ccnt     = (unsigned*)p; p += (size_t)NCHX * B * sizeof(unsigned);   // 64 KB
  unsigned* cand     = (unsigned*)p; p += (size_t)NCHX * B * CAPB * sizeof(unsigned); // 4 MB
  unsigned short* histg = (unsigned short*)p; p += (size_t)NCHX * B * NBK * sizeof(unsigned short); // 8 MB
  unsigned short* codes16 = (unsigned short*)p;                                  // 12.8 MB

  KArgs ka;
  ka.x = x; ka.W = W; ka.codes = codes; ka.labels = labels; ka.Kp = Kp;
  ka.out64 = out64; ka.rowTH = rowTH; ka.out16 = out16; ka.B1sq = B1sq;
  ka.shiftp = shiftp; ka.cmaxSlab = cmaxSlab; ka.belowCnt = belowCnt;
  ka.ccnt = ccnt; ka.cand = cand; ka.histg = histg; ka.codes16 = codes16;
  ka.gbar = gbar; ka.outp = (float*)d_out;
  ka.N = N; ka.Npad = Npad; ka.cpb = cpb; ka.B = B; ka.D = D; ka.nCvt = nCvt;

  void* args[] = { &ka };
  int nblk = NCHX * (B / MROWS);             // 512 blocks, 2/CU co-resident
  hipLaunchCooperativeKernel((void*)k_fused, dim3(nblk), dim3(256), args, 0, stream);
}

// Round 4
// 345.268 us; speedup vs baseline: 1.4831x; 1.4831x over previous
//
#include <hip/hip_runtime.h>
#include <hip/hip_fp16.h>

// B=256 queries, D=2048, d=64 hash dim, N=100000 database, C=100 classes,
// K=1000 SMALLEST-sim selection. Inputs f32, labels int, output f32.
//
// R10: back to plain dispatches (R7/R9 proved in-kernel grid sync costs
// ~70-95us/barrier regardless of implementation — worse than dispatch
// boundaries). Pipeline restructured from 8 dispatches down to THREE by
// storing the pass-1 bucket id per (row,n) as u8 (25.6MB), so pass 2 never
// recomputes MFMA:
//   k_prep    : detect + codes f32->f16 (+max||c||^2 slab) + out=x@W f64/f16
//   k_mhist   : MFMA screen -> u8 bucket[B][N] + u16 hist slabs [NCHX][B][NBK]
//   k_rowfinal: per-row block: sum own hist slabs (scan folded in), stream
//               bucket row: bk<=tb-1-q => below (label hist), bk<=tb+1+q =>
//               candidate (LDS queue), exact f64 resolve + bitonic, emit.
// Bucket-unit classification with q=ceil((2M+1e-3)/bw) is a conservative
// superset of R6's [TL,TH] window (~4 buckets ~ 700 cands/row; CAPC=2048).
// No memset, no global atomics, no cooperative launch; poison-safe (all
// state written before read each iteration).

#define NBK 256          // buckets per row histogram (pow2, == blockDim)
#define CAPC 2048        // per-row candidate capacity (expected ~700)
#define MROWS 32         // out-rows per MFMA block (two 16-row tiles)
#define NCHX 64          // code-chunks for MFMA pass
#define NCLS 100

typedef _Float16 half8 __attribute__((ext_vector_type(8)));
typedef float floatx4 __attribute__((ext_vector_type(4)));

static __device__ __forceinline__ unsigned packh2(float a, float b) {
  _Float16 ha = (_Float16)a, hb = (_Float16)b;      // RNE
  unsigned short ua, ub;
  __builtin_memcpy(&ua, &ha, 2); __builtin_memcpy(&ub, &hb, 2);
  return (unsigned)ua | ((unsigned)ub << 16);
}

// shared range math (1-ulp discrepancies absorbed by margins; M>=0.05)
static __device__ __forceinline__ void rowRange(double b1sq, double cmax,
                                                double& lo, double& inv, double& bw) {
  double hr = 0.5 * sqrt(b1sq * cmax) * 1.000001 + 9.0;  // +9 >> M
  lo = 50.0 - hr;
  bw = (2.0 * hr) / (double)NBK;
  inv = (double)NBK / (2.0 * hr);
}

// exact f64 dot for candidate resolution (order-stable chain)
static __device__ __forceinline__ double dot1(const float* __restrict__ codes, int n,
                                              const double* __restrict__ od) {
  const float4* crow = (const float4*)(codes + (size_t)n * 64);
  double a = 0.0;
#pragma unroll
  for (int i = 0; i < 16; ++i) {
    float4 q = crow[i];
    a = fma((double)q.x, od[i*4+0], a);
    a = fma((double)q.y, od[i*4+1], a);
    a = fma((double)q.z, od[i*4+2], a);
    a = fma((double)q.w, od[i*4+3], a);
  }
  return a;
}

// ---- MFMA A-fragment loader (mfma_f32_16x16x32_f16 layout, m89-verified):
//   A: lane holds A[m = lane&15][k = (lane>>4)*8 + j]; D: reg r = D[(lane>>4)*4+r][lane&15]
static __device__ __forceinline__ void loadA(const unsigned short* __restrict__ out16,
                                             int m0, int mr, int quad,
                                             half8& a00, half8& a01, half8& a10, half8& a11) {
  const uint4* o4 = (const uint4*)out16;
  uint4 u;
  u = o4[(size_t)(m0 + mr) * 8 + quad];          __builtin_memcpy(&a00, &u, 16);
  u = o4[(size_t)(m0 + mr) * 8 + 4 + quad];      __builtin_memcpy(&a01, &u, 16);
  u = o4[(size_t)(m0 + 16 + mr) * 8 + quad];     __builtin_memcpy(&a10, &u, 16);
  u = o4[(size_t)(m0 + 16 + mr) * 8 + 4 + quad]; __builtin_memcpy(&a11, &u, 16);
}

// deterministic max over the cvtnorm slab (order-independent fmaxf; bit-identical
// wherever called — same algorithm, same input)
static __device__ __forceinline__ float reduceCmax(const float* __restrict__ slab,
                                                   int n, float* fred) {
  int tid = (int)threadIdx.x;
  float m = 0.0f;
  for (int i = tid; i < n; i += 256) m = fmaxf(m, slab[i]);
  fred[tid] = m; __syncthreads();
  for (int off = 128; off > 0; off >>= 1) {
    if (tid < off) fred[tid] = fmaxf(fred[tid], fred[tid + off]);
    __syncthreads();
  }
  float r = fred[0];
  __syncthreads();
  return r;
}

// ============ k_prep: detect + cvtnorm + out, disjoint block ranges ============
__global__ __launch_bounds__(256) void k_prep(const float* __restrict__ x,
                                              const float* __restrict__ W,
                                              const float* __restrict__ codes,
                                              const int* __restrict__ labels,
                                              int N, int Npad, int D, int B, int nCvt,
                                              unsigned short* __restrict__ codes16,
                                              float* __restrict__ cmaxSlab,
                                              double* __restrict__ out64,
                                              unsigned short* __restrict__ out16,
                                              double* __restrict__ B1sq,
                                              int* __restrict__ shiftp) {
  __shared__ double red[256];
  __shared__ float fred[256];
  __shared__ int flag;
  int blk = (int)blockIdx.x, tid = (int)threadIdx.x;
  if (blk < nCvt) {              // codes f32 -> f16 (RNE) + per-block max ||code||^2
    int n = blk * 256 + tid;
    float m = 0.0f;
    if (n < N) {
      const float4* crow = (const float4*)(codes + (size_t)n * 64);
      uint4* orow = (uint4*)(codes16 + (size_t)n * 64);
      double c2 = 0.0;
#pragma unroll
      for (int i = 0; i < 8; ++i) {
        float4 qa = crow[2*i], qb = crow[2*i+1];
        c2 = fma((double)qa.x, (double)qa.x, c2); c2 = fma((double)qa.y, (double)qa.y, c2);
        c2 = fma((double)qa.z, (double)qa.z, c2); c2 = fma((double)qa.w, (double)qa.w, c2);
        c2 = fma((double)qb.x, (double)qb.x, c2); c2 = fma((double)qb.y, (double)qb.y, c2);
        c2 = fma((double)qb.z, (double)qb.z, c2); c2 = fma((double)qb.w, (double)qb.w, c2);
        uint4 o;
        o.x = packh2(qa.x, qa.y); o.y = packh2(qa.z, qa.w);
        o.z = packh2(qb.x, qb.y); o.w = packh2(qb.z, qb.w);
        orow[i] = o;
      }
      m = (float)(c2 * 1.000001);
    } else {                     // n < Npad always here
      uint4* orow = (uint4*)(codes16 + (size_t)n * 64);
      uint4 z = {0u, 0u, 0u, 0u};
#pragma unroll
      for (int i = 0; i < 8; ++i) orow[i] = z;
    }
    fred[tid] = m; __syncthreads();
    for (int off = 128; off > 0; off >>= 1) {
      if (tid < off) fred[tid] = fmaxf(fred[tid], fred[tid + off]);
      __syncthreads();
    }
    if (tid == 0) cmaxSlab[blk] = fred[0];   // plain store (no init needed)
  } else if (blk < nCvt + B) {   // out = x @ W in f64 (+f16 copy), ||out_b||^2
    int b = blk - nCvt;
    int t = tid & 63, w = tid >> 6;    // w in 0..3
    int kc = D >> 2;                   // 512 for D=2048
    int k0 = w * kc;
    const float* xr = x + (size_t)b * D;
    double a[8];
#pragma unroll
    for (int j = 0; j < 8; ++j) a[j] = 0.0;
    for (int k = k0; k < k0 + kc; k += 8) {
      float4 xv0 = *(const float4*)(xr + k);
      float4 xv1 = *(const float4*)(xr + k + 4);
      float xs[8] = {xv0.x, xv0.y, xv0.z, xv0.w, xv1.x, xv1.y, xv1.z, xv1.w};
#pragma unroll
      for (int j = 0; j < 8; ++j)
        a[j] = fma((double)xs[j], (double)W[(size_t)(k + j) * 64 + t], a[j]);
    }
    red[tid] = ((a[0] + a[1]) + (a[2] + a[3])) + ((a[4] + a[5]) + (a[6] + a[7]));
    __syncthreads();
    if (w == 0) {
      double o = 0.0;
#pragma unroll
      for (int j = 0; j < 4; ++j) o += red[t + 64 * j];
      out64[(size_t)b * 64 + t] = o;
      _Float16 h = (_Float16)(float)o;       // RNE
      unsigned short us; __builtin_memcpy(&us, &h, 2);
      out16[(size_t)b * 64 + t] = us;
      red[t] = o * o;                        // same-wave lanes: lockstep-safe
    }
    __syncthreads();
    if (tid == 0) {
      double s = 0.0;
      for (int i = 0; i < 64; ++i) s += red[i];
      B1sq[b] = s;
    }
  } else {                       // labels layout: int64 pairs vs int32
    if (tid == 0) flag = 0;
    __syncthreads();
    int m = N < 256 ? N : 256;
    if (tid < m && labels[2 * tid + 1] != 0) atomicOr(&flag, 1);
    __syncthreads();
    if (tid == 0) *shiftp = flag ? 0 : 1;    // label(n)=labels[n<<shift]
  }
}

// ============ k_mhist: MFMA screen -> u8 bucket array + u16 hist slabs ============
__global__ __launch_bounds__(256) void k_mhist(const unsigned short* __restrict__ codes16,
                                               const unsigned short* __restrict__ out16,
                                               const double* __restrict__ B1sq,
                                               const float* __restrict__ cmaxSlab,
                                               int nCvt, int N, int Npad, int cpb, int B,
                                               unsigned short* __restrict__ histg,
                                               unsigned char* __restrict__ buck) {
  __shared__ unsigned hist[MROWS * NBK];   // 32 KB
  __shared__ float sP[MROWS], sQ[MROWS], fred[256];
  int tid = (int)threadIdx.x;
  int m0 = (int)blockIdx.y * MROWS, cx = (int)blockIdx.x;
  float cmax = reduceCmax(cmaxSlab, nCvt, fred);
  for (int i = tid; i < MROWS * NBK; i += 256) hist[i] = 0u;
  if (tid < MROWS) {
    double lo, inv, bw;
    rowRange(B1sq[m0 + tid], (double)cmax, lo, inv, bw);
    sP[tid] = (float)(-0.5 * inv);         // bucket = trunc(d*P + Q), monotone in v
    sQ[tid] = (float)((50.0 - lo) * inv);
  }
  __syncthreads();
  int l = tid & 63, w = tid >> 6;
  int quad = l >> 4, mr = l & 15;
  half8 a00, a01, a10, a11;
  loadA(out16, m0, mr, quad, a00, a01, a10, a11);
  float P0[4], Q0[4], P1[4], Q1[4];
#pragma unroll
  for (int r = 0; r < 4; ++r) {
    P0[r] = sP[quad*4 + r];      Q0[r] = sQ[quad*4 + r];
    P1[r] = sP[16 + quad*4 + r]; Q1[r] = sQ[16 + quad*4 + r];
  }
  int cstart = cx * cpb;
  int cend = cstart + cpb; if (cend > N) cend = N;
  const uint4* c4 = (const uint4*)codes16;
  floatx4 z = {0.f, 0.f, 0.f, 0.f};
  for (int base = cstart; base < cend; base += 64) {
    int nrow = base + w * 16 + mr;
    int nc = nrow < Npad ? nrow : Npad - 1;
    uint4 ub0 = c4[(size_t)nc * 8 + quad];
    uint4 ub1 = c4[(size_t)nc * 8 + 4 + quad];
    half8 b0, b1;
    __builtin_memcpy(&b0, &ub0, 16); __builtin_memcpy(&b1, &ub1, 16);
    floatx4 d0 = __builtin_amdgcn_mfma_f32_16x16x32_f16(a00, b0, z, 0, 0, 0);
    d0 = __builtin_amdgcn_mfma_f32_16x16x32_f16(a01, b1, d0, 0, 0, 0);
    floatx4 d1 = __builtin_amdgcn_mfma_f32_16x16x32_f16(a10, b0, z, 0, 0, 0);
    d1 = __builtin_amdgcn_mfma_f32_16x16x32_f16(a11, b1, d1, 0, 0, 0);
    if (nrow < N) {
#pragma unroll
      for (int r = 0; r < 4; ++r) {
        int bk0 = (int)fmaf(d0[r], P0[r], Q0[r]);
        bk0 = bk0 < 0 ? 0 : (bk0 > NBK-1 ? NBK-1 : bk0);
        atomicAdd(&hist[(quad*4 + r) * NBK + bk0], 1u);   // LDS: local, fast
        buck[(size_t)(m0 + quad*4 + r) * N + nrow] = (unsigned char)bk0;
        int bk1 = (int)fmaf(d1[r], P1[r], Q1[r]);
        bk1 = bk1 < 0 ? 0 : (bk1 > NBK-1 ? NBK-1 : bk1);
        atomicAdd(&hist[(16 + quad*4 + r) * NBK + bk1], 1u);
        buck[(size_t)(m0 + 16 + quad*4 + r) * N + nrow] = (unsigned char)bk1;
      }
    }
  }
  __syncthreads();
  // exclusive slab, plain coalesced u16 stores (counts <= cpb=1600 < 65535)
  for (int i = tid; i < MROWS * NBK; i += 256)
    histg[((size_t)cx * B + (m0 + (i >> 8))) * NBK + (i & (NBK - 1))] =
        (unsigned short)hist[i];
}

// ============ k_rowfinal: one block per row — scan + classify + exact resolve ============
__global__ __launch_bounds__(256) void k_rowfinal(const float* __restrict__ codes,
                                                  const double* __restrict__ out64,
                                                  const double* __restrict__ B1sq,
                                                  const float* __restrict__ cmaxSlab,
                                                  const unsigned short* __restrict__ histg,
                                                  const unsigned char* __restrict__ buck,
                                                  const int* __restrict__ labels,
                                                  const int* __restrict__ shiftp,
                                                  const int* __restrict__ Kp,
                                                  float* __restrict__ outp,
                                                  int nCvt, int N, int B) {
  __shared__ unsigned s[NBK];
  __shared__ float fred[256];
  __shared__ double key[CAPC];
  __shared__ int kidx[CAPC];
  __shared__ unsigned lab[NCLS];
  __shared__ unsigned cnt;
  __shared__ int sTb;
  int b = (int)blockIdx.x, tid = (int)threadIdx.x;
  float cmax = reduceCmax(cmaxSlab, nCvt, fred);
  // row histogram: sum the 64 chunk slabs (coalesced u16, L2)
  unsigned acc = 0;
  for (int cx = 0; cx < NCHX; ++cx)
    acc += (unsigned)histg[((size_t)cx * B + b) * NBK + tid];
  s[tid] = acc;
  if (tid == 0) cnt = 0u;
  for (int i = tid; i < NCLS; i += 256) lab[i] = 0u;
  __syncthreads();
  for (int off = 1; off < NBK; off <<= 1) {    // inclusive prefix scan
    unsigned add = (tid >= off) ? s[tid - off] : 0u;
    __syncthreads();
    s[tid] += add;
    __syncthreads();
  }
  unsigned K = (unsigned)Kp[0];
  unsigned cum = s[tid], prev = tid ? s[tid - 1] : 0u;
  if (cum >= K && prev < K) sTb = tid;         // exactly one thread (total = N >= K)
  __syncthreads();
  int tb = sTb;
  // bucket-unit classification margins (conservative superset of R6's [TL,TH])
  double lo, inv, bw;
  rowRange(B1sq[b], (double)cmax, lo, inv, bw);
  double S = sqrt(B1sq[b] * (double)cmax);
  double Mtot = 2.0 * (0.5 * S * 1.1e-3 + 0.05) + 1e-3;  // 2M + abs slack
  int q = (int)ceil(Mtot / bw);
  int belowMax = tb - 1 - q;                   // bk <= belowMax -> certainly in top-K
  int candMax  = tb + 1 + q;                   // bk <= candMax  -> candidate
  if (candMax > NBK - 1) candMax = NBK - 1;
  unsigned btot = (belowMax >= 0) ? s[belowMax] : 0u;
  int shift = *shiftp;
  // stream the bucket row (u32 vector loads; N % 4 == 0 path + scalar tail)
  const unsigned* bw4 = (const unsigned*)(buck + (size_t)b * N);
  int nw = N >> 2;
  for (int i = tid; i < nw; i += 256) {
    unsigned wv = bw4[i];
#pragma unroll
    for (int j = 0; j < 4; ++j) {
      int bk = (int)((wv >> (8 * j)) & 0xFFu);
      if (bk <= belowMax) {
        atomicAdd(&lab[labels[(size_t)(4*i + j) << shift]], 1u);   // LDS
      } else if (bk <= candMax) {
        unsigned pos = atomicAdd(&cnt, 1u);                        // LDS
        if (pos < CAPC) kidx[pos] = 4*i + j;
      }
    }
  }
  for (int n = (nw << 2) + tid; n < N; n += 256) {    // tail (no-op for N%4==0)
    int bk = (int)buck[(size_t)b * N + n];
    if (bk <= belowMax) atomicAdd(&lab[labels[(size_t)n << shift]], 1u);
    else if (bk <= candMax) {
      unsigned pos = atomicAdd(&cnt, 1u);
      if (pos < CAPC) kidx[pos] = n;
    }
  }
  __syncthreads();
  int cc = (int)cnt; if (cc > CAPC) cc = CAPC;
  int need = (int)K - (int)btot;               // >= 1 (btot <= K-1 by construction)
  int M = 1; while (M < cc) M <<= 1;
  const double* od = out64 + (size_t)b * 64;
  for (int i = tid; i < M; i += 256) {
    if (i < cc) key[i] = fma(dot1(codes, kidx[i], od), -0.5, 50.0);
    else { key[i] = __builtin_inf(); kidx[i] = 0x7FFFFFFF; }
  }
  __syncthreads();
  for (int size = 2; size <= M; size <<= 1) {  // bitonic by (key, idx) asc
    for (int stride = size >> 1; stride > 0; stride >>= 1) {
      for (int i = tid; i < M; i += 256) {
        int j = i ^ stride;
        if (j > i) {
          double ki = key[i], kj = key[j];
          int ii = kidx[i], ij = kidx[j];
          bool up = ((i & size) == 0);
          bool sw = up ? (kj < ki || (kj == ki && ij < ii))
                       : (kj > ki || (kj == ki && ij > ii));
          if (sw) { key[i] = kj; key[j] = ki; kidx[i] = ij; kidx[j] = ii; }
        }
      }
      __syncthreads();
    }
  }
  int take = need < cc ? need : cc;
  if (take < 0) take = 0;
  for (int i = tid; i < take; i += 256)
    atomicAdd(&lab[labels[(size_t)kidx[i] << shift]], 1u);
  __syncthreads();
  double Kd = (double)K;
  for (int c = tid; c < NCLS; c += 256)
    outp[b * NCLS + c] = (float)((double)lab[c] / Kd);
}

extern "C" void kernel_launch(void* const* d_in, const int* in_sizes, int n_in,
                              void* d_out, int out_size, void* d_ws, size_t ws_size,
                              hipStream_t stream) {
  const float* x     = (const float*)d_in[0];
  const float* W     = (const float*)d_in[1];
  const float* codes = (const float*)d_in[2];
  const int* labels  = (const int*)d_in[3];
  const int* Kp      = (const int*)d_in[4];

  const int B = out_size / NCLS;             // 256
  const int N = in_sizes[3];                 // 100000
  const int D = in_sizes[0] / B;             // 2048
  const int Npad = (N + 255) & ~255;         // 100096
  const int cpb = (((N + NCHX - 1) / NCHX) + 63) & ~63;  // 1600 codes per chunk
  const int nCvt = Npad / 256;               // 391 cvtnorm blocks

  // ws layout; nothing needs host-side init (all state written before read).
  char* p = (char*)d_ws;
  double* out64      = (double*)p;   p += (size_t)B * 64 * sizeof(double);       // 128 KB
  unsigned short* out16 = (unsigned short*)p; p += (size_t)B * 64 * 2;           // 32 KB
  double* B1sq       = (double*)p;   p += (size_t)B * sizeof(double);            // 2 KB
  int* shiftp        = (int*)p;      p += 64;
  float* cmaxSlab    = (float*)p;    p += 4096;                                  // nCvt floats
  unsigned short* histg = (unsigned short*)p; p += (size_t)NCHX * B * NBK * 2;   // 8 MB
  unsigned char* buck   = (unsigned char*)p;  p += (size_t)B * N;                // 25.6 MB
  unsigned short* codes16 = (unsigned short*)p;                                  // 12.8 MB

  k_prep<<<nCvt + B + 1, 256, 0, stream>>>(x, W, codes, labels, N, Npad, D, B, nCvt,
                                           codes16, cmaxSlab, out64, out16, B1sq, shiftp);
  k_mhist<<<dim3(NCHX, B / MROWS), 256, 0, stream>>>(codes16, out16, B1sq, cmaxSlab,
                                                     nCvt, N, Npad, cpb, B, histg, buck);
  k_rowfinal<<<B, 256, 0, stream>>>(codes, out64, B1sq, cmaxSlab, histg, buck,
                                    labels, shiftp, Kp, (float*)d_out, nCvt, N, B);
}

// Round 5
// 218.117 us; speedup vs baseline: 2.3476x; 1.5829x over previous
//
#include <hip/hip_runtime.h>
#include <hip/hip_fp16.h>

// B=256 queries, D=2048, d=64 hash dim, N=100000 database, C=100 classes,
// K=1000 SMALLEST-sim selection. Inputs f32, labels int, output f32.
//
// R11: 3-dispatch pipeline (R10 shape). k_rowfinal rebuilt for latency:
// R10 PMC showed 218us @ 10% occupancy, all pipes idle (1 block/CU, 4 waves,
// ~98 serial branchy iterations + uncoalesced per-thread f64 dots).
// Now: 1024 thr/block (16 waves/CU), bucket stream via 7 up-front uint4
// loads/thread (statically indexed regs), below-idx LDS queue (label gather
// moved out of hot loop, exec-full), candidate dots by 16-lane groups
// (coalesced 256B row reads + shfl butterfly), hist sum split 4-way.
//   k_prep    : detect + codes f32->f16 (+max||c||^2 slab) + out=x@W f64/f16
//   k_mhist   : MFMA screen -> u8 bucket[B][N] + u16 hist slabs [NCHX][B][NBK]
//   k_rowfinal: per-row: slab-sum+scan -> tb -> stream buck -> below/cand ->
//               exact f64 group-dot resolve + bitonic -> label hist -> probs
// No memset, no global atomics, no cooperative launch; poison-safe.

#define NBK 256          // buckets per row histogram (pow2)
#define CAPC 2048        // per-row candidate capacity (expected ~900)
#define BCAP 2048        // per-row below-list capacity (btot < K <= 2048 assumed)
#define MROWS 32         // out-rows per MFMA block (two 16-row tiles)
#define NCHX 64          // code-chunks for MFMA pass
#define NCLS 100

typedef _Float16 half8 __attribute__((ext_vector_type(8)));
typedef float floatx4 __attribute__((ext_vector_type(4)));

static __device__ __forceinline__ unsigned packh2(float a, float b) {
  _Float16 ha = (_Float16)a, hb = (_Float16)b;      // RNE
  unsigned short ua, ub;
  __builtin_memcpy(&ua, &ha, 2); __builtin_memcpy(&ub, &hb, 2);
  return (unsigned)ua | ((unsigned)ub << 16);
}

// shared range math (1-ulp discrepancies absorbed by margins; M>=0.05)
static __device__ __forceinline__ void rowRange(double b1sq, double cmax,
                                                double& lo, double& inv, double& bw) {
  double hr = 0.5 * sqrt(b1sq * cmax) * 1.000001 + 9.0;  // +9 >> M
  lo = 50.0 - hr;
  bw = (2.0 * hr) / (double)NBK;
  inv = (double)NBK / (2.0 * hr);
}

// ---- MFMA A-fragment loader (mfma_f32_16x16x32_f16 layout, m89-verified):
//   A: lane holds A[m = lane&15][k = (lane>>4)*8 + j]; D: reg r = D[(lane>>4)*4+r][lane&15]
static __device__ __forceinline__ void loadA(const unsigned short* __restrict__ out16,
                                             int m0, int mr, int quad,
                                             half8& a00, half8& a01, half8& a10, half8& a11) {
  const uint4* o4 = (const uint4*)out16;
  uint4 u;
  u = o4[(size_t)(m0 + mr) * 8 + quad];          __builtin_memcpy(&a00, &u, 16);
  u = o4[(size_t)(m0 + mr) * 8 + 4 + quad];      __builtin_memcpy(&a01, &u, 16);
  u = o4[(size_t)(m0 + 16 + mr) * 8 + quad];     __builtin_memcpy(&a10, &u, 16);
  u = o4[(size_t)(m0 + 16 + mr) * 8 + 4 + quad]; __builtin_memcpy(&a11, &u, 16);
}

// deterministic max over the cvtnorm slab, 256-thread version (k_mhist)
static __device__ __forceinline__ float reduceCmax256(const float* __restrict__ slab,
                                                      int n, float* fred) {
  int tid = (int)threadIdx.x;
  float m = 0.0f;
  for (int i = tid; i < n; i += 256) m = fmaxf(m, slab[i]);
  fred[tid] = m; __syncthreads();
  for (int off = 128; off > 0; off >>= 1) {
    if (tid < off) fred[tid] = fmaxf(fred[tid], fred[tid + off]);
    __syncthreads();
  }
  float r = fred[0];
  __syncthreads();
  return r;
}

// ============ k_prep: detect + cvtnorm + out, disjoint block ranges ============
__global__ __launch_bounds__(256) void k_prep(const float* __restrict__ x,
                                              const float* __restrict__ W,
                                              const float* __restrict__ codes,
                                              const int* __restrict__ labels,
                                              int N, int Npad, int D, int B, int nCvt,
                                              unsigned short* __restrict__ codes16,
                                              float* __restrict__ cmaxSlab,
                                              double* __restrict__ out64,
                                              unsigned short* __restrict__ out16,
                                              double* __restrict__ B1sq,
                                              int* __restrict__ shiftp) {
  __shared__ double red[256];
  __shared__ float fred[256];
  __shared__ int flag;
  int blk = (int)blockIdx.x, tid = (int)threadIdx.x;
  if (blk < nCvt) {              // codes f32 -> f16 (RNE) + per-block max ||code||^2
    int n = blk * 256 + tid;
    float m = 0.0f;
    if (n < N) {
      const float4* crow = (const float4*)(codes + (size_t)n * 64);
      uint4* orow = (uint4*)(codes16 + (size_t)n * 64);
      double c2 = 0.0;
#pragma unroll
      for (int i = 0; i < 8; ++i) {
        float4 qa = crow[2*i], qb = crow[2*i+1];
        c2 = fma((double)qa.x, (double)qa.x, c2); c2 = fma((double)qa.y, (double)qa.y, c2);
        c2 = fma((double)qa.z, (double)qa.z, c2); c2 = fma((double)qa.w, (double)qa.w, c2);
        c2 = fma((double)qb.x, (double)qb.x, c2); c2 = fma((double)qb.y, (double)qb.y, c2);
        c2 = fma((double)qb.z, (double)qb.z, c2); c2 = fma((double)qb.w, (double)qb.w, c2);
        uint4 o;
        o.x = packh2(qa.x, qa.y); o.y = packh2(qa.z, qa.w);
        o.z = packh2(qb.x, qb.y); o.w = packh2(qb.z, qb.w);
        orow[i] = o;
      }
      m = (float)(c2 * 1.000001);
    } else {                     // n < Npad always here
      uint4* orow = (uint4*)(codes16 + (size_t)n * 64);
      uint4 z = {0u, 0u, 0u, 0u};
#pragma unroll
      for (int i = 0; i < 8; ++i) orow[i] = z;
    }
    fred[tid] = m; __syncthreads();
    for (int off = 128; off > 0; off >>= 1) {
      if (tid < off) fred[tid] = fmaxf(fred[tid], fred[tid + off]);
      __syncthreads();
    }
    if (tid == 0) cmaxSlab[blk] = fred[0];   // plain store (no init needed)
  } else if (blk < nCvt + B) {   // out = x @ W in f64 (+f16 copy), ||out_b||^2
    int b = blk - nCvt;
    int t = tid & 63, w = tid >> 6;    // w in 0..3
    int kc = D >> 2;                   // 512 for D=2048
    int k0 = w * kc;
    const float* xr = x + (size_t)b * D;
    double a[8];
#pragma unroll
    for (int j = 0; j < 8; ++j) a[j] = 0.0;
    for (int k = k0; k < k0 + kc; k += 8) {
      float4 xv0 = *(const float4*)(xr + k);
      float4 xv1 = *(const float4*)(xr + k + 4);
      float xs[8] = {xv0.x, xv0.y, xv0.z, xv0.w, xv1.x, xv1.y, xv1.z, xv1.w};
#pragma unroll
      for (int j = 0; j < 8; ++j)
        a[j] = fma((double)xs[j], (double)W[(size_t)(k + j) * 64 + t], a[j]);
    }
    red[tid] = ((a[0] + a[1]) + (a[2] + a[3])) + ((a[4] + a[5]) + (a[6] + a[7]));
    __syncthreads();
    if (w == 0) {
      double o = 0.0;
#pragma unroll
      for (int j = 0; j < 4; ++j) o += red[t + 64 * j];
      out64[(size_t)b * 64 + t] = o;
      _Float16 h = (_Float16)(float)o;       // RNE
      unsigned short us; __builtin_memcpy(&us, &h, 2);
      out16[(size_t)b * 64 + t] = us;
      red[t] = o * o;                        // same-wave lanes: lockstep-safe
    }
    __syncthreads();
    if (tid == 0) {
      double s = 0.0;
      for (int i = 0; i < 64; ++i) s += red[i];
      B1sq[b] = s;
    }
  } else {                       // labels layout: int64 pairs vs int32
    if (tid == 0) flag = 0;
    __syncthreads();
    int m = N < 256 ? N : 256;
    if (tid < m && labels[2 * tid + 1] != 0) atomicOr(&flag, 1);
    __syncthreads();
    if (tid == 0) *shiftp = flag ? 0 : 1;    // label(n)=labels[n<<shift]
  }
}

// ============ k_mhist: MFMA screen -> u8 bucket array + u16 hist slabs ============
__global__ __launch_bounds__(256) void k_mhist(const unsigned short* __restrict__ codes16,
                                               const unsigned short* __restrict__ out16,
                                               const double* __restrict__ B1sq,
                                               const float* __restrict__ cmaxSlab,
                                               int nCvt, int N, int Npad, int cpb, int B,
                                               unsigned short* __restrict__ histg,
                                               unsigned char* __restrict__ buck) {
  __shared__ unsigned hist[MROWS * NBK];   // 32 KB
  __shared__ float sP[MROWS], sQ[MROWS], fred[256];
  int tid = (int)threadIdx.x;
  int m0 = (int)blockIdx.y * MROWS, cx = (int)blockIdx.x;
  float cmax = reduceCmax256(cmaxSlab, nCvt, fred);
  for (int i = tid; i < MROWS * NBK; i += 256) hist[i] = 0u;
  if (tid < MROWS) {
    double lo, inv, bw;
    rowRange(B1sq[m0 + tid], (double)cmax, lo, inv, bw);
    sP[tid] = (float)(-0.5 * inv);         // bucket = trunc(d*P + Q), monotone in v
    sQ[tid] = (float)((50.0 - lo) * inv);
  }
  __syncthreads();
  int l = tid & 63, w = tid >> 6;
  int quad = l >> 4, mr = l & 15;
  half8 a00, a01, a10, a11;
  loadA(out16, m0, mr, quad, a00, a01, a10, a11);
  float P0[4], Q0[4], P1[4], Q1[4];
#pragma unroll
  for (int r = 0; r < 4; ++r) {
    P0[r] = sP[quad*4 + r];      Q0[r] = sQ[quad*4 + r];
    P1[r] = sP[16 + quad*4 + r]; Q1[r] = sQ[16 + quad*4 + r];
  }
  int cstart = cx * cpb;
  int cend = cstart + cpb; if (cend > N) cend = N;
  const uint4* c4 = (const uint4*)codes16;
  floatx4 z = {0.f, 0.f, 0.f, 0.f};
  for (int base = cstart; base < cend; base += 64) {
    int nrow = base + w * 16 + mr;
    int nc = nrow < Npad ? nrow : Npad - 1;
    uint4 ub0 = c4[(size_t)nc * 8 + quad];
    uint4 ub1 = c4[(size_t)nc * 8 + 4 + quad];
    half8 b0, b1;
    __builtin_memcpy(&b0, &ub0, 16); __builtin_memcpy(&b1, &ub1, 16);
    floatx4 d0 = __builtin_amdgcn_mfma_f32_16x16x32_f16(a00, b0, z, 0, 0, 0);
    d0 = __builtin_amdgcn_mfma_f32_16x16x32_f16(a01, b1, d0, 0, 0, 0);
    floatx4 d1 = __builtin_amdgcn_mfma_f32_16x16x32_f16(a10, b0, z, 0, 0, 0);
    d1 = __builtin_amdgcn_mfma_f32_16x16x32_f16(a11, b1, d1, 0, 0, 0);
    if (nrow < N) {
#pragma unroll
      for (int r = 0; r < 4; ++r) {
        int bk0 = (int)fmaf(d0[r], P0[r], Q0[r]);
        bk0 = bk0 < 0 ? 0 : (bk0 > NBK-1 ? NBK-1 : bk0);
        atomicAdd(&hist[(quad*4 + r) * NBK + bk0], 1u);   // LDS: local, fast
        buck[(size_t)(m0 + quad*4 + r) * N + nrow] = (unsigned char)bk0;
        int bk1 = (int)fmaf(d1[r], P1[r], Q1[r]);
        bk1 = bk1 < 0 ? 0 : (bk1 > NBK-1 ? NBK-1 : bk1);
        atomicAdd(&hist[(16 + quad*4 + r) * NBK + bk1], 1u);
        buck[(size_t)(m0 + 16 + quad*4 + r) * N + nrow] = (unsigned char)bk1;
      }
    }
  }
  __syncthreads();
  // exclusive slab, plain coalesced u16 stores (counts <= cpb=1600 < 65535)
  for (int i = tid; i < MROWS * NBK; i += 256)
    histg[((size_t)cx * B + (m0 + (i >> 8))) * NBK + (i & (NBK - 1))] =
        (unsigned short)hist[i];
}

// ============ k_rowfinal: one 1024-thr block per row ============
__global__ __launch_bounds__(1024) void k_rowfinal(const float* __restrict__ codes,
                                                   const double* __restrict__ out64,
                                                   const double* __restrict__ B1sq,
                                                   const float* __restrict__ cmaxSlab,
                                                   const unsigned short* __restrict__ histg,
                                                   const unsigned char* __restrict__ buck,
                                                   const int* __restrict__ labels,
                                                   const int* __restrict__ shiftp,
                                                   const int* __restrict__ Kp,
                                                   float* __restrict__ outp,
                                                   int nCvt, int N, int B) {
  __shared__ float fredf[1024];            // 4 KB (cmax reduce)
  __shared__ unsigned sp[1024];            // 4 KB (slab partials)
  __shared__ unsigned s[NBK];              // 1 KB (row hist / prefix)
  __shared__ double key[CAPC];             // 16 KB
  __shared__ int kidx[CAPC];               // 8 KB
  __shared__ int blist[BCAP];              // 8 KB (below-item indices)
  __shared__ double sod[64];               // 0.5 KB (out64 row)
  __shared__ unsigned lab[NCLS];
  __shared__ unsigned ccnt, bcnt;
  __shared__ int sTb;
  int b = (int)blockIdx.x, tid = (int)threadIdx.x;

  // deterministic cmax (same fmaxf tree as k_mhist? different width, but value
  // is an exact max — order-independent for fmaxf on finite floats)
  {
    float m = 0.0f;
    for (int i = tid; i < nCvt; i += 1024) m = fmaxf(m, cmaxSlab[i]);
    fredf[tid] = m; __syncthreads();
    for (int off = 512; off > 0; off >>= 1) {
      if (tid < off) fredf[tid] = fmaxf(fredf[tid], fredf[tid + off]);
      __syncthreads();
    }
  }
  float cmax = fredf[0];
  if (tid < 64) sod[tid] = out64[(size_t)b * 64 + tid];
  if (tid == 0) { ccnt = 0u; bcnt = 0u; }
  for (int i = tid; i < NCLS; i += 1024) lab[i] = 0u;

  // row histogram: 4-way split slab sum (16 chunk loads per thread)
  {
    int bk = tid & 255, cq = tid >> 8;     // cq in 0..3
    unsigned part = 0;
    for (int cx = cq * 16; cx < cq * 16 + 16; ++cx)
      part += (unsigned)histg[((size_t)cx * B + b) * NBK + bk];
    sp[tid] = part;
  }
  __syncthreads();
  if (tid < 256) s[tid] = sp[tid] + sp[tid + 256] + sp[tid + 512] + sp[tid + 768];
  __syncthreads();
  for (int off = 1; off < NBK; off <<= 1) {    // inclusive prefix scan (tid<256 work)
    unsigned add = (tid < 256 && tid >= off) ? s[tid - off] : 0u;
    __syncthreads();
    if (tid < 256) s[tid] += add;
    __syncthreads();
  }
  unsigned K = (unsigned)Kp[0];
  if (tid < 256) {
    unsigned cum = s[tid], prev = tid ? s[tid - 1] : 0u;
    if (cum >= K && prev < K) sTb = tid;       // exactly one thread
  }
  __syncthreads();
  int tb = sTb;
  // bucket-unit classification margins (conservative superset of [TL,TH])
  double lo, inv, bw;
  rowRange(B1sq[b], (double)cmax, lo, inv, bw);
  double S = sqrt(B1sq[b] * (double)cmax);
  double Mtot = 2.0 * (0.5 * S * 1.1e-3 + 0.05) + 1e-3;  // 2M + abs slack
  int q = (int)ceil(Mtot / bw);
  int belowMax = tb - 1 - q;                   // bk <= belowMax -> certainly in top-K
  int candMax  = tb + 1 + q;                   // bk <= candMax  -> candidate
  if (candMax > NBK - 1) candMax = NBK - 1;
  unsigned btot = (belowMax >= 0) ? s[belowMax] : 0u;
  int shift = *shiftp;

  // ---- stream bucket row: 7 uint4 loads/thread issued up-front (MLP) ----
  {
    const uint4* bw16 = (const uint4*)(buck + (size_t)b * N);
    int nw16 = N >> 4;
    uint4 vv0, vv1, vv2, vv3, vv4, vv5, vv6, vv7;
    int i0 = tid, i1 = tid + 1024, i2 = tid + 2048, i3 = tid + 3072;
    int i4 = tid + 4096, i5 = tid + 5120, i6 = tid + 6144, i7 = tid + 7168;
    if (i0 < nw16) vv0 = bw16[i0];
    if (i1 < nw16) vv1 = bw16[i1];
    if (i2 < nw16) vv2 = bw16[i2];
    if (i3 < nw16) vv3 = bw16[i3];
    if (i4 < nw16) vv4 = bw16[i4];
    if (i5 < nw16) vv5 = bw16[i5];
    if (i6 < nw16) vv6 = bw16[i6];
    if (i7 < nw16) vv7 = bw16[i7];
#define CLS1(nn, bkv)                                                     \
    { int bk_ = (int)(bkv);                                               \
      if (bk_ <= belowMax) {                                              \
        unsigned p_ = atomicAdd(&bcnt, 1u);                               \
        if (p_ < BCAP) blist[p_] = (nn);                                  \
      } else if (bk_ <= candMax) {                                        \
        unsigned p_ = atomicAdd(&ccnt, 1u);                               \
        if (p_ < CAPC) kidx[p_] = (nn);                                   \
      } }
#define CLSV(ii, vv)                                                      \
    if ((ii) < nw16) {                                                    \
      int nb_ = (ii) << 4;                                                \
      unsigned w_;                                                        \
      w_ = vv.x; CLS1(nb_+0,  w_ & 0xFF) CLS1(nb_+1,  (w_>>8) & 0xFF)     \
                 CLS1(nb_+2,  (w_>>16) & 0xFF) CLS1(nb_+3,  w_>>24)       \
      w_ = vv.y; CLS1(nb_+4,  w_ & 0xFF) CLS1(nb_+5,  (w_>>8) & 0xFF)     \
                 CLS1(nb_+6,  (w_>>16) & 0xFF) CLS1(nb_+7,  w_>>24)       \
      w_ = vv.z; CLS1(nb_+8,  w_ & 0xFF) CLS1(nb_+9,  (w_>>8) & 0xFF)     \
                 CLS1(nb_+10, (w_>>16) & 0xFF) CLS1(nb_+11, w_>>24)       \
      w_ = vv.w; CLS1(nb_+12, w_ & 0xFF) CLS1(nb_+13, (w_>>8) & 0xFF)     \
                 CLS1(nb_+14, (w_>>16) & 0xFF) CLS1(nb_+15, w_>>24)       \
    }
    CLSV(i0, vv0) CLSV(i1, vv1) CLSV(i2, vv2) CLSV(i3, vv3)
    CLSV(i4, vv4) CLSV(i5, vv5) CLSV(i6, vv6) CLSV(i7, vv7)
#undef CLSV
#undef CLS1
    for (int n = (nw16 << 4) + tid; n < N; n += 1024) {   // tail (none for N%16==0)
      int bk_ = (int)buck[(size_t)b * N + n];
      if (bk_ <= belowMax) {
        unsigned p_ = atomicAdd(&bcnt, 1u);
        if (p_ < BCAP) blist[p_] = n;
      } else if (bk_ <= candMax) {
        unsigned p_ = atomicAdd(&ccnt, 1u);
        if (p_ < CAPC) kidx[p_] = n;
      }
    }
  }
  __syncthreads();

  // ---- below labels: exec-full parallel gather ----
  {
    int bm = (int)bcnt; if (bm > BCAP) bm = BCAP;
    for (int i = tid; i < bm; i += 1024)
      atomicAdd(&lab[labels[(size_t)blist[i] << shift]], 1u);
  }

  int cc = (int)ccnt; if (cc > CAPC) cc = CAPC;
  int need = (int)K - (int)btot;               // >= 1
  int M = 1; while (M < cc) M <<= 1;
  // padding
  for (int i = cc + tid; i < M; i += 1024) { key[i] = __builtin_inf(); kidx[i] = 0x7FFFFFFF; }
  // ---- exact f64 dots: 16-lane groups, coalesced 256B row reads ----
  {
    int g = tid >> 4, gl = tid & 15;           // 64 groups x 16 lanes
    for (int i = g; i < cc; i += 64) {
      int n = kidx[i];
      float4 qv = ((const float4*)(codes + (size_t)n * 64))[gl];
      double p = fma((double)qv.x, sod[gl*4+0], 0.0);
      p = fma((double)qv.y, sod[gl*4+1], p);
      p = fma((double)qv.z, sod[gl*4+2], p);
      p = fma((double)qv.w, sod[gl*4+3], p);
      p += __shfl_xor(p, 1, 16);               // deterministic butterfly
      p += __shfl_xor(p, 2, 16);
      p += __shfl_xor(p, 4, 16);
      p += __shfl_xor(p, 8, 16);
      if (gl == 0) key[i] = fma(p, -0.5, 50.0);
    }
  }
  __syncthreads();
  // ---- bitonic by (key, idx) asc ----
  for (int size = 2; size <= M; size <<= 1) {
    for (int stride = size >> 1; stride > 0; stride >>= 1) {
      for (int i = tid; i < M; i += 1024) {
        int j = i ^ stride;
        if (j > i) {
          double ki = key[i], kj = key[j];
          int ii = kidx[i], ij = kidx[j];
          bool up = ((i & size) == 0);
          bool sw = up ? (kj < ki || (kj == ki && ij < ii))
                       : (kj > ki || (kj == ki && ij > ii));
          if (sw) { key[i] = kj; key[j] = ki; kidx[i] = ij; kidx[j] = ii; }
        }
      }
      __syncthreads();
    }
  }
  int take = need < cc ? need : cc;
  if (take < 0) take = 0;
  for (int i = tid; i < take; i += 1024)
    atomicAdd(&lab[labels[(size_t)kidx[i] << shift]], 1u);
  __syncthreads();
  double Kd = (double)K;
  for (int c = tid; c < NCLS; c += 1024)
    outp[b * NCLS + c] = (float)((double)lab[c] / Kd);
}

extern "C" void kernel_launch(void* const* d_in, const int* in_sizes, int n_in,
                              void* d_out, int out_size, void* d_ws, size_t ws_size,
                              hipStream_t stream) {
  const float* x     = (const float*)d_in[0];
  const float* W     = (const float*)d_in[1];
  const float* codes = (const float*)d_in[2];
  const int* labels  = (const int*)d_in[3];
  const int* Kp      = (const int*)d_in[4];

  const int B = out_size / NCLS;             // 256
  const int N = in_sizes[3];                 // 100000
  const int D = in_sizes[0] / B;             // 2048
  const int Npad = (N + 255) & ~255;         // 100096
  const int cpb = (((N + NCHX - 1) / NCHX) + 63) & ~63;  // 1600 codes per chunk
  const int nCvt = Npad / 256;               // 391 cvtnorm blocks

  // ws layout; nothing needs host-side init (all state written before read).
  char* p = (char*)d_ws;
  double* out64      = (double*)p;   p += (size_t)B * 64 * sizeof(double);       // 128 KB
  unsigned short* out16 = (unsigned short*)p; p += (size_t)B * 64 * 2;           // 32 KB
  double* B1sq       = (double*)p;   p += (size_t)B * sizeof(double);            // 2 KB
  int* shiftp        = (int*)p;      p += 64;
  float* cmaxSlab    = (float*)p;    p += 4096;                                  // nCvt floats
  unsigned short* histg = (unsigned short*)p; p += (size_t)NCHX * B * NBK * 2;   // 8 MB
  unsigned char* buck   = (unsigned char*)p;  p += (size_t)B * N;                // 25.6 MB
  unsigned short* codes16 = (unsigned short*)p;                                  // 12.8 MB

  k_prep<<<nCvt + B + 1, 256, 0, stream>>>(x, W, codes, labels, N, Npad, D, B, nCvt,
                                           codes16, cmaxSlab, out64, out16, B1sq, shiftp);
  k_mhist<<<dim3(NCHX, B / MROWS), 256, 0, stream>>>(codes16, out16, B1sq, cmaxSlab,
                                                     nCvt, N, Npad, cpb, B, histg, buck);
  k_rowfinal<<<B, 1024, 0, stream>>>(codes, out64, B1sq, cmaxSlab, histg, buck,
                                     labels, shiftp, Kp, (float*)d_out, nCvt, N, B);
}

// Round 6
// 167.003 us; speedup vs baseline: 3.0662x; 1.3061x over previous
//
#include <hip/hip_runtime.h>
#include <hip/hip_fp16.h>

// B=256 queries, D=2048, d=64 hash dim, N=100000 database, C=100 classes,
// K=1000 SMALLEST-sim selection. Inputs f32, labels int, output f32.
//
// R12: 3-dispatch pipeline (R10/R11 shape); k_rowfinal rebuilt for BARRIER
// count: R11 had ~92 __syncthreads (55 bitonic + 32 scan + trees) at 16
// waves/block -> ~50us of barrier drain. Now ~11 barriers:
//  - bitonic sort REPLACED by fine-bucket selection on exact f64 keys
//    (1024 fine buckets over the candidate range; monotone map; threshold
//    bucket rank-resolved by (key,idx) — lax.top_k tie-break preserved);
//  - all reductions/scans via intra-wave __shfl (no barriers) + one LDS
//    cross-wave combine each;
//  - classify stream: 2-deep unrolled uint4 loads for MLP.
//   k_prep    : detect + codes f32->f16 (+max||c||^2 slab) + out=x@W f64/f16
//   k_mhist   : MFMA screen -> u8 bucket[B][N] + u16 hist slabs [NCHX][B][NBK]
//   k_rowfinal: per-row: slab-sum+scan -> tb -> stream buck -> below/cand ->
//               f64 group-dots -> fine-bucket select -> label hist -> probs
// No memset, no global atomics, no cooperative launch; poison-safe.

#define NBK 256          // coarse buckets per row histogram (pow2)
#define FNB 1024         // fine buckets for candidate selection (pow2)
#define CAPC 2048        // per-row candidate capacity (expected ~900)
#define BCAP 2048        // per-row below-list capacity (btot < K)
#define MROWS 32         // out-rows per MFMA block (two 16-row tiles)
#define NCHX 64          // code-chunks for MFMA pass
#define NCLS 100

typedef _Float16 half8 __attribute__((ext_vector_type(8)));
typedef float floatx4 __attribute__((ext_vector_type(4)));

static __device__ __forceinline__ unsigned packh2(float a, float b) {
  _Float16 ha = (_Float16)a, hb = (_Float16)b;      // RNE
  unsigned short ua, ub;
  __builtin_memcpy(&ua, &ha, 2); __builtin_memcpy(&ub, &hb, 2);
  return (unsigned)ua | ((unsigned)ub << 16);
}

// shared range math (1-ulp discrepancies absorbed by margins; M>=0.05)
static __device__ __forceinline__ void rowRange(double b1sq, double cmax,
                                                double& lo, double& inv, double& bw) {
  double hr = 0.5 * sqrt(b1sq * cmax) * 1.000001 + 9.0;  // +9 >> M
  lo = 50.0 - hr;
  bw = (2.0 * hr) / (double)NBK;
  inv = (double)NBK / (2.0 * hr);
}

// ---- MFMA A-fragment loader (mfma_f32_16x16x32_f16 layout, m89-verified):
//   A: lane holds A[m = lane&15][k = (lane>>4)*8 + j]; D: reg r = D[(lane>>4)*4+r][lane&15]
static __device__ __forceinline__ void loadA(const unsigned short* __restrict__ out16,
                                             int m0, int mr, int quad,
                                             half8& a00, half8& a01, half8& a10, half8& a11) {
  const uint4* o4 = (const uint4*)out16;
  uint4 u;
  u = o4[(size_t)(m0 + mr) * 8 + quad];          __builtin_memcpy(&a00, &u, 16);
  u = o4[(size_t)(m0 + mr) * 8 + 4 + quad];      __builtin_memcpy(&a01, &u, 16);
  u = o4[(size_t)(m0 + 16 + mr) * 8 + quad];     __builtin_memcpy(&a10, &u, 16);
  u = o4[(size_t)(m0 + 16 + mr) * 8 + 4 + quad]; __builtin_memcpy(&a11, &u, 16);
}

// deterministic max over the cvtnorm slab, 256-thread version (k_mhist)
static __device__ __forceinline__ float reduceCmax256(const float* __restrict__ slab,
                                                      int n, float* fred) {
  int tid = (int)threadIdx.x;
  float m = 0.0f;
  for (int i = tid; i < n; i += 256) m = fmaxf(m, slab[i]);
  fred[tid] = m; __syncthreads();
  for (int off = 128; off > 0; off >>= 1) {
    if (tid < off) fred[tid] = fmaxf(fred[tid], fred[tid + off]);
    __syncthreads();
  }
  float r = fred[0];
  __syncthreads();
  return r;
}

// ============ k_prep: detect + cvtnorm + out, disjoint block ranges ============
__global__ __launch_bounds__(256) void k_prep(const float* __restrict__ x,
                                              const float* __restrict__ W,
                                              const float* __restrict__ codes,
                                              const int* __restrict__ labels,
                                              int N, int Npad, int D, int B, int nCvt,
                                              unsigned short* __restrict__ codes16,
                                              float* __restrict__ cmaxSlab,
                                              double* __restrict__ out64,
                                              unsigned short* __restrict__ out16,
                                              double* __restrict__ B1sq,
                                              int* __restrict__ shiftp) {
  __shared__ double red[256];
  __shared__ float fred[256];
  __shared__ int flag;
  int blk = (int)blockIdx.x, tid = (int)threadIdx.x;
  if (blk < nCvt) {              // codes f32 -> f16 (RNE) + per-block max ||code||^2
    int n = blk * 256 + tid;
    float m = 0.0f;
    if (n < N) {
      const float4* crow = (const float4*)(codes + (size_t)n * 64);
      uint4* orow = (uint4*)(codes16 + (size_t)n * 64);
      double c2 = 0.0;
#pragma unroll
      for (int i = 0; i < 8; ++i) {
        float4 qa = crow[2*i], qb = crow[2*i+1];
        c2 = fma((double)qa.x, (double)qa.x, c2); c2 = fma((double)qa.y, (double)qa.y, c2);
        c2 = fma((double)qa.z, (double)qa.z, c2); c2 = fma((double)qa.w, (double)qa.w, c2);
        c2 = fma((double)qb.x, (double)qb.x, c2); c2 = fma((double)qb.y, (double)qb.y, c2);
        c2 = fma((double)qb.z, (double)qb.z, c2); c2 = fma((double)qb.w, (double)qb.w, c2);
        uint4 o;
        o.x = packh2(qa.x, qa.y); o.y = packh2(qa.z, qa.w);
        o.z = packh2(qb.x, qb.y); o.w = packh2(qb.z, qb.w);
        orow[i] = o;
      }
      m = (float)(c2 * 1.000001);
    } else {                     // n < Npad always here
      uint4* orow = (uint4*)(codes16 + (size_t)n * 64);
      uint4 z = {0u, 0u, 0u, 0u};
#pragma unroll
      for (int i = 0; i < 8; ++i) orow[i] = z;
    }
    fred[tid] = m; __syncthreads();
    for (int off = 128; off > 0; off >>= 1) {
      if (tid < off) fred[tid] = fmaxf(fred[tid], fred[tid + off]);
      __syncthreads();
    }
    if (tid == 0) cmaxSlab[blk] = fred[0];   // plain store (no init needed)
  } else if (blk < nCvt + B) {   // out = x @ W in f64 (+f16 copy), ||out_b||^2
    int b = blk - nCvt;
    int t = tid & 63, w = tid >> 6;    // w in 0..3
    int kc = D >> 2;                   // 512 for D=2048
    int k0 = w * kc;
    const float* xr = x + (size_t)b * D;
    double a[8];
#pragma unroll
    for (int j = 0; j < 8; ++j) a[j] = 0.0;
    for (int k = k0; k < k0 + kc; k += 8) {
      float4 xv0 = *(const float4*)(xr + k);
      float4 xv1 = *(const float4*)(xr + k + 4);
      float xs[8] = {xv0.x, xv0.y, xv0.z, xv0.w, xv1.x, xv1.y, xv1.z, xv1.w};
#pragma unroll
      for (int j = 0; j < 8; ++j)
        a[j] = fma((double)xs[j], (double)W[(size_t)(k + j) * 64 + t], a[j]);
    }
    red[tid] = ((a[0] + a[1]) + (a[2] + a[3])) + ((a[4] + a[5]) + (a[6] + a[7]));
    __syncthreads();
    if (w == 0) {
      double o = 0.0;
#pragma unroll
      for (int j = 0; j < 4; ++j) o += red[t + 64 * j];
      out64[(size_t)b * 64 + t] = o;
      _Float16 h = (_Float16)(float)o;       // RNE
      unsigned short us; __builtin_memcpy(&us, &h, 2);
      out16[(size_t)b * 64 + t] = us;
      red[t] = o * o;                        // same-wave lanes: lockstep-safe
    }
    __syncthreads();
    if (tid == 0) {
      double s = 0.0;
      for (int i = 0; i < 64; ++i) s += red[i];
      B1sq[b] = s;
    }
  } else {                       // labels layout: int64 pairs vs int32
    if (tid == 0) flag = 0;
    __syncthreads();
    int m = N < 256 ? N : 256;
    if (tid < m && labels[2 * tid + 1] != 0) atomicOr(&flag, 1);
    __syncthreads();
    if (tid == 0) *shiftp = flag ? 0 : 1;    // label(n)=labels[n<<shift]
  }
}

// ============ k_mhist: MFMA screen -> u8 bucket array + u16 hist slabs ============
__global__ __launch_bounds__(256) void k_mhist(const unsigned short* __restrict__ codes16,
                                               const unsigned short* __restrict__ out16,
                                               const double* __restrict__ B1sq,
                                               const float* __restrict__ cmaxSlab,
                                               int nCvt, int N, int Npad, int cpb, int B,
                                               unsigned short* __restrict__ histg,
                                               unsigned char* __restrict__ buck) {
  __shared__ unsigned hist[MROWS * NBK];   // 32 KB
  __shared__ float sP[MROWS], sQ[MROWS], fred[256];
  int tid = (int)threadIdx.x;
  int m0 = (int)blockIdx.y * MROWS, cx = (int)blockIdx.x;
  float cmax = reduceCmax256(cmaxSlab, nCvt, fred);
  for (int i = tid; i < MROWS * NBK; i += 256) hist[i] = 0u;
  if (tid < MROWS) {
    double lo, inv, bw;
    rowRange(B1sq[m0 + tid], (double)cmax, lo, inv, bw);
    sP[tid] = (float)(-0.5 * inv);         // bucket = trunc(d*P + Q), monotone in v
    sQ[tid] = (float)((50.0 - lo) * inv);
  }
  __syncthreads();
  int l = tid & 63, w = tid >> 6;
  int quad = l >> 4, mr = l & 15;
  half8 a00, a01, a10, a11;
  loadA(out16, m0, mr, quad, a00, a01, a10, a11);
  float P0[4], Q0[4], P1[4], Q1[4];
#pragma unroll
  for (int r = 0; r < 4; ++r) {
    P0[r] = sP[quad*4 + r];      Q0[r] = sQ[quad*4 + r];
    P1[r] = sP[16 + quad*4 + r]; Q1[r] = sQ[16 + quad*4 + r];
  }
  int cstart = cx * cpb;
  int cend = cstart + cpb; if (cend > N) cend = N;
  const uint4* c4 = (const uint4*)codes16;
  floatx4 z = {0.f, 0.f, 0.f, 0.f};
  for (int base = cstart; base < cend; base += 64) {
    int nrow = base + w * 16 + mr;
    int nc = nrow < Npad ? nrow : Npad - 1;
    uint4 ub0 = c4[(size_t)nc * 8 + quad];
    uint4 ub1 = c4[(size_t)nc * 8 + 4 + quad];
    half8 b0, b1;
    __builtin_memcpy(&b0, &ub0, 16); __builtin_memcpy(&b1, &ub1, 16);
    floatx4 d0 = __builtin_amdgcn_mfma_f32_16x16x32_f16(a00, b0, z, 0, 0, 0);
    d0 = __builtin_amdgcn_mfma_f32_16x16x32_f16(a01, b1, d0, 0, 0, 0);
    floatx4 d1 = __builtin_amdgcn_mfma_f32_16x16x32_f16(a10, b0, z, 0, 0, 0);
    d1 = __builtin_amdgcn_mfma_f32_16x16x32_f16(a11, b1, d1, 0, 0, 0);
    if (nrow < N) {
#pragma unroll
      for (int r = 0; r < 4; ++r) {
        int bk0 = (int)fmaf(d0[r], P0[r], Q0[r]);
        bk0 = bk0 < 0 ? 0 : (bk0 > NBK-1 ? NBK-1 : bk0);
        atomicAdd(&hist[(quad*4 + r) * NBK + bk0], 1u);   // LDS: local, fast
        buck[(size_t)(m0 + quad*4 + r) * N + nrow] = (unsigned char)bk0;
        int bk1 = (int)fmaf(d1[r], P1[r], Q1[r]);
        bk1 = bk1 < 0 ? 0 : (bk1 > NBK-1 ? NBK-1 : bk1);
        atomicAdd(&hist[(16 + quad*4 + r) * NBK + bk1], 1u);
        buck[(size_t)(m0 + 16 + quad*4 + r) * N + nrow] = (unsigned char)bk1;
      }
    }
  }
  __syncthreads();
  // exclusive slab, plain coalesced u16 stores (counts <= cpb=1600 < 65535)
  for (int i = tid; i < MROWS * NBK; i += 256)
    histg[((size_t)cx * B + (m0 + (i >> 8))) * NBK + (i & (NBK - 1))] =
        (unsigned short)hist[i];
}

// ============ k_rowfinal v2: one 1024-thr block per row, ~11 barriers ============
__global__ __launch_bounds__(1024) void k_rowfinal(const float* __restrict__ codes,
                                                   const double* __restrict__ out64,
                                                   const double* __restrict__ B1sq,
                                                   const float* __restrict__ cmaxSlab,
                                                   const unsigned short* __restrict__ histg,
                                                   const unsigned char* __restrict__ buck,
                                                   const int* __restrict__ labels,
                                                   const int* __restrict__ shiftp,
                                                   const int* __restrict__ Kp,
                                                   float* __restrict__ outp,
                                                   int nCvt, int N, int B) {
  __shared__ float fredw[16];
  __shared__ unsigned sp[1024];            // slab partials; reused for fine scan
  __shared__ unsigned s[NBK];              // coarse cumulative hist
  __shared__ unsigned wtot[4];
  __shared__ double key[CAPC];             // 16 KB
  __shared__ int kidx[CAPC];               // 8 KB
  __shared__ int blist[BCAP];              // 8 KB
  __shared__ unsigned fhist[FNB];          // 4 KB
  __shared__ unsigned ftot[16];
  __shared__ unsigned short tlist[CAPC];   // 4 KB (indices into key/kidx)
  __shared__ double sod[64];
  __shared__ unsigned lab[NCLS];
  __shared__ unsigned ccnt, bcnt, tcnt, sCntLt;
  __shared__ int sTb, sFtb;
  int b = (int)blockIdx.x, tid = (int)threadIdx.x;
  int lane = tid & 63, wid = tid >> 6;

  // ---- init + cmax wave-reduce (order-independent exact max) ----
  {
    float m = (tid < nCvt) ? cmaxSlab[tid] : 0.0f;
    for (int i = tid + 1024; i < nCvt; i += 1024) m = fmaxf(m, cmaxSlab[i]);
#pragma unroll
    for (int off = 32; off > 0; off >>= 1) m = fmaxf(m, __shfl_xor(m, off, 64));
    if (lane == 0) fredw[wid] = m;
  }
  fhist[tid] = 0u;
  if (tid < 64) sod[tid] = out64[(size_t)b * 64 + tid];
  if (tid < NCLS) lab[tid] = 0u;
  if (tid == 0) { ccnt = 0u; bcnt = 0u; tcnt = 0u; sCntLt = 0u; sFtb = FNB; }
  __syncthreads();                                         // 1
  float cmax;
  { float m = fredw[0];
#pragma unroll
    for (int j = 1; j < 16; ++j) m = fmaxf(m, fredw[j]);
    cmax = m; }

  // ---- coarse slab sum (4-way split, 16 coalesced u16 loads/thread) ----
  {
    int bk = tid & 255, cq = tid >> 8;
    unsigned part = 0;
#pragma unroll
    for (int t2 = 0; t2 < 16; ++t2)
      part += (unsigned)histg[((size_t)(cq * 16 + t2) * B + b) * NBK + bk];
    sp[tid] = part;
  }
  __syncthreads();                                         // 2
  {
    unsigned v = 0;
    if (tid < 256) {
      v = sp[tid] + sp[tid + 256] + sp[tid + 512] + sp[tid + 768];
#pragma unroll
      for (int off = 1; off < 64; off <<= 1) {             // wave inclusive scan
        unsigned t = (unsigned)__shfl_up((int)v, off, 64);
        if (lane >= off) v += t;
      }
      if (lane == 63) wtot[wid] = v;
    }
    __syncthreads();                                       // 3
    if (tid < 256) {
      for (int j = 0; j < wid; ++j) v += wtot[j];
      s[tid] = v;                                          // inclusive cumulative
    }
  }
  __syncthreads();                                         // 4
  unsigned K = (unsigned)Kp[0];
  if (tid < 256) {
    unsigned prev = tid ? s[tid - 1] : 0u;
    if (s[tid] >= K && prev < K) sTb = tid;                // exactly one thread
  }
  __syncthreads();                                         // 5
  int tb = sTb;
  double lo, inv, bwd;
  rowRange(B1sq[b], (double)cmax, lo, inv, bwd);
  double S = sqrt(B1sq[b] * (double)cmax);
  double Mtot = 2.0 * (0.5 * S * 1.1e-3 + 0.05) + 1e-3;    // 2M + abs slack
  int q = (int)ceil(Mtot / bwd);
  int belowMax = tb - 1 - q;                               // certainly in top-K
  int candMax = tb + 1 + q;                                // candidate window
  if (candMax > NBK - 1) candMax = NBK - 1;
  unsigned btot = (belowMax >= 0) ? s[belowMax] : 0u;
  int shift = *shiftp;

  // ---- classify stream: 2-deep MLP grid-stride uint4 ----
  {
    const uint4* bw16 = (const uint4*)(buck + (size_t)b * N);
    int nw16 = N >> 4;
#define CLS1(nn, bkv)                                                  \
    { int bk_ = (int)(bkv);                                            \
      if (bk_ <= belowMax) {                                           \
        unsigned p_ = atomicAdd(&bcnt, 1u);                            \
        if (p_ < BCAP) blist[p_] = (nn);                               \
      } else if (bk_ <= candMax) {                                     \
        unsigned p_ = atomicAdd(&ccnt, 1u);                            \
        if (p_ < CAPC) kidx[p_] = (nn);                                \
      } }
#define PROCV(vv, nb)                                                  \
    { unsigned w_;                                                     \
      w_ = (vv).x; CLS1((nb)+0,  w_ & 0xFF) CLS1((nb)+1,  (w_>>8)&0xFF)\
                   CLS1((nb)+2,  (w_>>16)&0xFF) CLS1((nb)+3,  w_>>24)  \
      w_ = (vv).y; CLS1((nb)+4,  w_ & 0xFF) CLS1((nb)+5,  (w_>>8)&0xFF)\
                   CLS1((nb)+6,  (w_>>16)&0xFF) CLS1((nb)+7,  w_>>24)  \
      w_ = (vv).z; CLS1((nb)+8,  w_ & 0xFF) CLS1((nb)+9,  (w_>>8)&0xFF)\
                   CLS1((nb)+10, (w_>>16)&0xFF) CLS1((nb)+11, w_>>24)  \
      w_ = (vv).w; CLS1((nb)+12, w_ & 0xFF) CLS1((nb)+13, (w_>>8)&0xFF)\
                   CLS1((nb)+14, (w_>>16)&0xFF) CLS1((nb)+15, w_>>24) }
    for (int i = tid; i < nw16; i += 2048) {
      uint4 v0 = bw16[i];
      int i1 = i + 1024; bool h1 = i1 < nw16;
      uint4 v1 = {0u, 0u, 0u, 0u};
      if (h1) v1 = bw16[i1];
      PROCV(v0, i << 4)
      if (h1) PROCV(v1, i1 << 4)
    }
#undef PROCV
    for (int n = (nw16 << 4) + tid; n < N; n += 1024) {    // tail
      CLS1(n, buck[(size_t)b * N + n])
    }
#undef CLS1
  }
  __syncthreads();                                         // 6

  // ---- below labels (exec-full) + candidate exact dots (independent) ----
  {
    int bm = (int)bcnt; if (bm > BCAP) bm = BCAP;
    for (int i = tid; i < bm; i += 1024)
      atomicAdd(&lab[labels[(size_t)blist[i] << shift]], 1u);
  }
  int cc = (int)ccnt; if (cc > CAPC) cc = CAPC;
  {
    int g = tid >> 4, gl = tid & 15;                       // 64 groups x 16 lanes
    for (int i = g; i < cc; i += 64) {
      int n = kidx[i];
      float4 qv = ((const float4*)(codes + (size_t)n * 64))[gl];
      double p = fma((double)qv.x, sod[gl*4+0], 0.0);
      p = fma((double)qv.y, sod[gl*4+1], p);
      p = fma((double)qv.z, sod[gl*4+2], p);
      p = fma((double)qv.w, sod[gl*4+3], p);
      p += __shfl_xor(p, 1, 16);                           // deterministic butterfly
      p += __shfl_xor(p, 2, 16);
      p += __shfl_xor(p, 4, 16);
      p += __shfl_xor(p, 8, 16);
      if (gl == 0) key[i] = fma(p, -0.5, 50.0);
    }
  }
  __syncthreads();                                         // 7

  // ---- fine-bucket selection over exact keys (monotone map) ----
  int need = (int)K - (int)btot;                           // >= 1
  double fLo = lo + (double)(belowMax + 1) * bwd - Mtot;
  double fInv = (double)FNB / ((double)(candMax - belowMax) * bwd + 2.0 * Mtot);
  for (int i = tid; i < cc; i += 1024) {
    int fb = (int)((key[i] - fLo) * fInv);
    fb = fb < 0 ? 0 : (fb > FNB - 1 ? FNB - 1 : fb);
    atomicAdd(&fhist[fb], 1u);
  }
  __syncthreads();                                         // 8
  {
    unsigned v = fhist[tid];
#pragma unroll
    for (int off = 1; off < 64; off <<= 1) {
      unsigned t = (unsigned)__shfl_up((int)v, off, 64);
      if (lane >= off) v += t;
    }
    if (lane == 63) ftot[wid] = v;
    sp[tid] = v;                                           // wave-local inclusive
  }
  __syncthreads();                                         // 9
  {
    unsigned off = 0;
    for (int j = 0; j < wid; ++j) off += ftot[j];
    unsigned ci = sp[tid] + off;                           // inclusive cum
    unsigned ce = ci - fhist[tid];                         // exclusive cum
    if ((int)ci >= need && (int)ce < need) { sFtb = tid; sCntLt = ce; }
  }
  __syncthreads();                                         // 10
  int ftb = sFtb;
  // emit: certain candidates -> labels; threshold fine-bucket -> tlist
  for (int i = tid; i < cc; i += 1024) {
    int fb = (int)((key[i] - fLo) * fInv);
    fb = fb < 0 ? 0 : (fb > FNB - 1 ? FNB - 1 : fb);
    if (fb < ftb) {
      atomicAdd(&lab[labels[(size_t)kidx[i] << shift]], 1u);
    } else if (fb == ftb) {
      unsigned p_ = atomicAdd(&tcnt, 1u);
      if (p_ < CAPC) tlist[p_] = (unsigned short)i;
    }
  }
  __syncthreads();                                         // 11
  {
    int tn = (int)tcnt; if (tn > CAPC) tn = CAPC;
    int rem = need - (int)sCntLt;                          // in [1, fhist[ftb]]
    for (int j = tid; j < tn; j += 1024) {
      int i = (int)tlist[j];
      double ki = key[i]; int ii = kidx[i];
      int rank = 0;
      for (int j2 = 0; j2 < tn; ++j2) {
        int i2 = (int)tlist[j2];
        double k2 = key[i2];
        rank += (k2 < ki || (k2 == ki && kidx[i2] < ii)) ? 1 : 0;
      }
      if (rank < rem) atomicAdd(&lab[labels[(size_t)ii << shift]], 1u);
    }
  }
  __syncthreads();                                         // 12
  double Kd = (double)K;
  for (int c = tid; c < NCLS; c += 1024)
    outp[b * NCLS + c] = (float)((double)lab[c] / Kd);
}

extern "C" void kernel_launch(void* const* d_in, const int* in_sizes, int n_in,
                              void* d_out, int out_size, void* d_ws, size_t ws_size,
                              hipStream_t stream) {
  const float* x     = (const float*)d_in[0];
  const float* W     = (const float*)d_in[1];
  const float* codes = (const float*)d_in[2];
  const int* labels  = (const int*)d_in[3];
  const int* Kp      = (const int*)d_in[4];

  const int B = out_size / NCLS;             // 256
  const int N = in_sizes[3];                 // 100000
  const int D = in_sizes[0] / B;             // 2048
  const int Npad = (N + 255) & ~255;         // 100096
  const int cpb = (((N + NCHX - 1) / NCHX) + 63) & ~63;  // 1600 codes per chunk
  const int nCvt = Npad / 256;               // 391 cvtnorm blocks

  // ws layout; nothing needs host-side init (all state written before read).
  char* p = (char*)d_ws;
  double* out64      = (double*)p;   p += (size_t)B * 64 * sizeof(double);       // 128 KB
  unsigned short* out16 = (unsigned short*)p; p += (size_t)B * 64 * 2;           // 32 KB
  double* B1sq       = (double*)p;   p += (size_t)B * sizeof(double);            // 2 KB
  int* shiftp        = (int*)p;      p += 64;
  float* cmaxSlab    = (float*)p;    p += 4096;                                  // nCvt floats
  unsigned short* histg = (unsigned short*)p; p += (size_t)NCHX * B * NBK * 2;   // 8 MB
  unsigned char* buck   = (unsigned char*)p;  p += (size_t)B * N;                // 25.6 MB
  unsigned short* codes16 = (unsigned short*)p;                                  // 12.8 MB

  k_prep<<<nCvt + B + 1, 256, 0, stream>>>(x, W, codes, labels, N, Npad, D, B, nCvt,
                                           codes16, cmaxSlab, out64, out16, B1sq, shiftp);
  k_mhist<<<dim3(NCHX, B / MROWS), 256, 0, stream>>>(codes16, out16, B1sq, cmaxSlab,
                                                     nCvt, N, Npad, cpb, B, histg, buck);
  k_rowfinal<<<B, 1024, 0, stream>>>(codes, out64, B1sq, cmaxSlab, histg, buck,
                                     labels, shiftp, Kp, (float*)d_out, nCvt, N, B);
}

// Round 7
// 160.419 us; speedup vs baseline: 3.1920x; 1.0410x over previous
//
#include <hip/hip_runtime.h>
#include <hip/hip_fp16.h>

// B=256 queries, D=2048, d=64 hash dim, N=100000 database, C=100 classes,
// K=1000 SMALLEST-sim selection. Inputs f32, labels int, output f32.
//
// R13: R12 pipeline (3 dispatches, ~12-barrier rowfinal) with k_prep's cvt
// section COALESCED: R12 PMC showed k_prep = 47us @ 932 GB/s (row-per-thread
// stride-256B float4 loads = 64 lines/instr). Now 16 lanes per row: per pass
// a block loads 4KB contiguous (float4/lane), packs, stores 2KB contiguous
// (uint2/lane); norm via 4 f64 FMA/lane + 4-step width-16 shfl_xor reduce.
//   k_prep    : detect + codes f32->f16 (+max||c||^2 slab) + out=x@W f64/f16
//   k_mhist   : MFMA screen -> u8 bucket[B][N] + u16 hist slabs [NCHX][B][NBK]
//   k_rowfinal: per-row: slab-sum+scan -> tb -> stream buck -> below/cand ->
//               f64 group-dots -> fine-bucket select -> label hist -> probs
// No memset, no global atomics, no cooperative launch; poison-safe.

#define NBK 256          // coarse buckets per row histogram (pow2)
#define FNB 1024         // fine buckets for candidate selection (pow2)
#define CAPC 2048        // per-row candidate capacity (expected ~900)
#define BCAP 2048        // per-row below-list capacity (btot < K)
#define MROWS 32         // out-rows per MFMA block (two 16-row tiles)
#define NCHX 64          // code-chunks for MFMA pass
#define NCLS 100

typedef _Float16 half8 __attribute__((ext_vector_type(8)));
typedef float floatx4 __attribute__((ext_vector_type(4)));

static __device__ __forceinline__ unsigned packh2(float a, float b) {
  _Float16 ha = (_Float16)a, hb = (_Float16)b;      // RNE
  unsigned short ua, ub;
  __builtin_memcpy(&ua, &ha, 2); __builtin_memcpy(&ub, &hb, 2);
  return (unsigned)ua | ((unsigned)ub << 16);
}

// shared range math (1-ulp discrepancies absorbed by margins; M>=0.05)
static __device__ __forceinline__ void rowRange(double b1sq, double cmax,
                                                double& lo, double& inv, double& bw) {
  double hr = 0.5 * sqrt(b1sq * cmax) * 1.000001 + 9.0;  // +9 >> M
  lo = 50.0 - hr;
  bw = (2.0 * hr) / (double)NBK;
  inv = (double)NBK / (2.0 * hr);
}

// ---- MFMA A-fragment loader (mfma_f32_16x16x32_f16 layout, m89-verified):
//   A: lane holds A[m = lane&15][k = (lane>>4)*8 + j]; D: reg r = D[(lane>>4)*4+r][lane&15]
static __device__ __forceinline__ void loadA(const unsigned short* __restrict__ out16,
                                             int m0, int mr, int quad,
                                             half8& a00, half8& a01, half8& a10, half8& a11) {
  const uint4* o4 = (const uint4*)out16;
  uint4 u;
  u = o4[(size_t)(m0 + mr) * 8 + quad];          __builtin_memcpy(&a00, &u, 16);
  u = o4[(size_t)(m0 + mr) * 8 + 4 + quad];      __builtin_memcpy(&a01, &u, 16);
  u = o4[(size_t)(m0 + 16 + mr) * 8 + quad];     __builtin_memcpy(&a10, &u, 16);
  u = o4[(size_t)(m0 + 16 + mr) * 8 + 4 + quad]; __builtin_memcpy(&a11, &u, 16);
}

// deterministic max over the cvtnorm slab, 256-thread version (k_mhist)
static __device__ __forceinline__ float reduceCmax256(const float* __restrict__ slab,
                                                      int n, float* fred) {
  int tid = (int)threadIdx.x;
  float m = 0.0f;
  for (int i = tid; i < n; i += 256) m = fmaxf(m, slab[i]);
  fred[tid] = m; __syncthreads();
  for (int off = 128; off > 0; off >>= 1) {
    if (tid < off) fred[tid] = fmaxf(fred[tid], fred[tid + off]);
    __syncthreads();
  }
  float r = fred[0];
  __syncthreads();
  return r;
}

// ============ k_prep: detect + cvtnorm (coalesced) + out ============
__global__ __launch_bounds__(256) void k_prep(const float* __restrict__ x,
                                              const float* __restrict__ W,
                                              const float* __restrict__ codes,
                                              const int* __restrict__ labels,
                                              int N, int Npad, int D, int B, int nCvt,
                                              unsigned short* __restrict__ codes16,
                                              float* __restrict__ cmaxSlab,
                                              double* __restrict__ out64,
                                              unsigned short* __restrict__ out16,
                                              double* __restrict__ B1sq,
                                              int* __restrict__ shiftp) {
  __shared__ double red[256];
  __shared__ float fredw[4];
  __shared__ int flag;
  int blk = (int)blockIdx.x, tid = (int)threadIdx.x;
  if (blk < nCvt) {
    // 16 lanes per row; 16 passes x 16 rows: fully coalesced (4KB ld / 2KB st)
    int gl = tid & 15, g = tid >> 4;
    int base = blk * 256;
    float bmax = 0.0f;
#pragma unroll
    for (int p = 0; p < 16; ++p) {
      int row = base + p * 16 + g;               // < Npad always
      float4 qv = {0.f, 0.f, 0.f, 0.f};
      if (row < N) qv = ((const float4*)(codes + (size_t)row * 64))[gl];
      uint2 o;
      o.x = packh2(qv.x, qv.y);
      o.y = packh2(qv.z, qv.w);
      ((uint2*)(codes16 + (size_t)row * 64))[gl] = o;
      double c2 = fma((double)qv.x, (double)qv.x, 0.0);
      c2 = fma((double)qv.y, (double)qv.y, c2);
      c2 = fma((double)qv.z, (double)qv.z, c2);
      c2 = fma((double)qv.w, (double)qv.w, c2);
      c2 += __shfl_xor(c2, 1, 16);               // deterministic 16-lane reduce
      c2 += __shfl_xor(c2, 2, 16);
      c2 += __shfl_xor(c2, 4, 16);
      c2 += __shfl_xor(c2, 8, 16);
      bmax = fmaxf(bmax, (float)(c2 * 1.000001));
    }
    // block max: wave reduce + tiny LDS combine (exact max, order-independent)
    int lane = tid & 63, wid = tid >> 6;
#pragma unroll
    for (int off = 32; off > 0; off >>= 1) bmax = fmaxf(bmax, __shfl_xor(bmax, off, 64));
    if (lane == 0) fredw[wid] = bmax;
    __syncthreads();
    if (tid == 0)
      cmaxSlab[blk] = fmaxf(fmaxf(fredw[0], fredw[1]), fmaxf(fredw[2], fredw[3]));
  } else if (blk < nCvt + B) {   // out = x @ W in f64 (+f16 copy), ||out_b||^2
    int b = blk - nCvt;
    int t = tid & 63, w = tid >> 6;    // w in 0..3
    int kc = D >> 2;                   // 512 for D=2048
    int k0 = w * kc;
    const float* xr = x + (size_t)b * D;
    double a[8];
#pragma unroll
    for (int j = 0; j < 8; ++j) a[j] = 0.0;
    for (int k = k0; k < k0 + kc; k += 8) {
      float4 xv0 = *(const float4*)(xr + k);
      float4 xv1 = *(const float4*)(xr + k + 4);
      float xs[8] = {xv0.x, xv0.y, xv0.z, xv0.w, xv1.x, xv1.y, xv1.z, xv1.w};
#pragma unroll
      for (int j = 0; j < 8; ++j)
        a[j] = fma((double)xs[j], (double)W[(size_t)(k + j) * 64 + t], a[j]);
    }
    red[tid] = ((a[0] + a[1]) + (a[2] + a[3])) + ((a[4] + a[5]) + (a[6] + a[7]));
    __syncthreads();
    if (w == 0) {
      double o = 0.0;
#pragma unroll
      for (int j = 0; j < 4; ++j) o += red[t + 64 * j];
      out64[(size_t)b * 64 + t] = o;
      _Float16 h = (_Float16)(float)o;       // RNE
      unsigned short us; __builtin_memcpy(&us, &h, 2);
      out16[(size_t)b * 64 + t] = us;
      red[t] = o * o;                        // same-wave lanes: lockstep-safe
    }
    __syncthreads();
    if (tid == 0) {
      double s = 0.0;
      for (int i = 0; i < 64; ++i) s += red[i];
      B1sq[b] = s;
    }
  } else {                       // labels layout: int64 pairs vs int32
    if (tid == 0) flag = 0;
    __syncthreads();
    int m = N < 256 ? N : 256;
    if (tid < m && labels[2 * tid + 1] != 0) atomicOr(&flag, 1);
    __syncthreads();
    if (tid == 0) *shiftp = flag ? 0 : 1;    // label(n)=labels[n<<shift]
  }
}

// ============ k_mhist: MFMA screen -> u8 bucket array + u16 hist slabs ============
__global__ __launch_bounds__(256) void k_mhist(const unsigned short* __restrict__ codes16,
                                               const unsigned short* __restrict__ out16,
                                               const double* __restrict__ B1sq,
                                               const float* __restrict__ cmaxSlab,
                                               int nCvt, int N, int Npad, int cpb, int B,
                                               unsigned short* __restrict__ histg,
                                               unsigned char* __restrict__ buck) {
  __shared__ unsigned hist[MROWS * NBK];   // 32 KB
  __shared__ float sP[MROWS], sQ[MROWS], fred[256];
  int tid = (int)threadIdx.x;
  int m0 = (int)blockIdx.y * MROWS, cx = (int)blockIdx.x;
  float cmax = reduceCmax256(cmaxSlab, nCvt, fred);
  for (int i = tid; i < MROWS * NBK; i += 256) hist[i] = 0u;
  if (tid < MROWS) {
    double lo, inv, bw;
    rowRange(B1sq[m0 + tid], (double)cmax, lo, inv, bw);
    sP[tid] = (float)(-0.5 * inv);         // bucket = trunc(d*P + Q), monotone in v
    sQ[tid] = (float)((50.0 - lo) * inv);
  }
  __syncthreads();
  int l = tid & 63, w = tid >> 6;
  int quad = l >> 4, mr = l & 15;
  half8 a00, a01, a10, a11;
  loadA(out16, m0, mr, quad, a00, a01, a10, a11);
  float P0[4], Q0[4], P1[4], Q1[4];
#pragma unroll
  for (int r = 0; r < 4; ++r) {
    P0[r] = sP[quad*4 + r];      Q0[r] = sQ[quad*4 + r];
    P1[r] = sP[16 + quad*4 + r]; Q1[r] = sQ[16 + quad*4 + r];
  }
  int cstart = cx * cpb;
  int cend = cstart + cpb; if (cend > N) cend = N;
  const uint4* c4 = (const uint4*)codes16;
  floatx4 z = {0.f, 0.f, 0.f, 0.f};
  for (int base = cstart; base < cend; base += 64) {
    int nrow = base + w * 16 + mr;
    int nc = nrow < Npad ? nrow : Npad - 1;
    uint4 ub0 = c4[(size_t)nc * 8 + quad];
    uint4 ub1 = c4[(size_t)nc * 8 + 4 + quad];
    half8 b0, b1;
    __builtin_memcpy(&b0, &ub0, 16); __builtin_memcpy(&b1, &ub1, 16);
    floatx4 d0 = __builtin_amdgcn_mfma_f32_16x16x32_f16(a00, b0, z, 0, 0, 0);
    d0 = __builtin_amdgcn_mfma_f32_16x16x32_f16(a01, b1, d0, 0, 0, 0);
    floatx4 d1 = __builtin_amdgcn_mfma_f32_16x16x32_f16(a10, b0, z, 0, 0, 0);
    d1 = __builtin_amdgcn_mfma_f32_16x16x32_f16(a11, b1, d1, 0, 0, 0);
    if (nrow < N) {
#pragma unroll
      for (int r = 0; r < 4; ++r) {
        int bk0 = (int)fmaf(d0[r], P0[r], Q0[r]);
        bk0 = bk0 < 0 ? 0 : (bk0 > NBK-1 ? NBK-1 : bk0);
        atomicAdd(&hist[(quad*4 + r) * NBK + bk0], 1u);   // LDS: local, fast
        buck[(size_t)(m0 + quad*4 + r) * N + nrow] = (unsigned char)bk0;
        int bk1 = (int)fmaf(d1[r], P1[r], Q1[r]);
        bk1 = bk1 < 0 ? 0 : (bk1 > NBK-1 ? NBK-1 : bk1);
        atomicAdd(&hist[(16 + quad*4 + r) * NBK + bk1], 1u);
        buck[(size_t)(m0 + 16 + quad*4 + r) * N + nrow] = (unsigned char)bk1;
      }
    }
  }
  __syncthreads();
  // exclusive slab, plain coalesced u16 stores (counts <= cpb=1600 < 65535)
  for (int i = tid; i < MROWS * NBK; i += 256)
    histg[((size_t)cx * B + (m0 + (i >> 8))) * NBK + (i & (NBK - 1))] =
        (unsigned short)hist[i];
}

// ============ k_rowfinal: one 1024-thr block per row, ~12 barriers ============
__global__ __launch_bounds__(1024) void k_rowfinal(const float* __restrict__ codes,
                                                   const double* __restrict__ out64,
                                                   const double* __restrict__ B1sq,
                                                   const float* __restrict__ cmaxSlab,
                                                   const unsigned short* __restrict__ histg,
                                                   const unsigned char* __restrict__ buck,
                                                   const int* __restrict__ labels,
                                                   const int* __restrict__ shiftp,
                                                   const int* __restrict__ Kp,
                                                   float* __restrict__ outp,
                                                   int nCvt, int N, int B) {
  __shared__ float fredw[16];
  __shared__ unsigned sp[1024];            // slab partials; reused for fine scan
  __shared__ unsigned s[NBK];              // coarse cumulative hist
  __shared__ unsigned wtot[4];
  __shared__ double key[CAPC];             // 16 KB
  __shared__ int kidx[CAPC];               // 8 KB
  __shared__ int blist[BCAP];              // 8 KB
  __shared__ unsigned fhist[FNB];          // 4 KB
  __shared__ unsigned ftot[16];
  __shared__ unsigned short tlist[CAPC];   // 4 KB (indices into key/kidx)
  __shared__ double sod[64];
  __shared__ unsigned lab[NCLS];
  __shared__ unsigned ccnt, bcnt, tcnt, sCntLt;
  __shared__ int sTb, sFtb;
  int b = (int)blockIdx.x, tid = (int)threadIdx.x;
  int lane = tid & 63, wid = tid >> 6;

  // ---- init + cmax wave-reduce (order-independent exact max) ----
  {
    float m = (tid < nCvt) ? cmaxSlab[tid] : 0.0f;
    for (int i = tid + 1024; i < nCvt; i += 1024) m = fmaxf(m, cmaxSlab[i]);
#pragma unroll
    for (int off = 32; off > 0; off >>= 1) m = fmaxf(m, __shfl_xor(m, off, 64));
    if (lane == 0) fredw[wid] = m;
  }
  fhist[tid] = 0u;
  if (tid < 64) sod[tid] = out64[(size_t)b * 64 + tid];
  if (tid < NCLS) lab[tid] = 0u;
  if (tid == 0) { ccnt = 0u; bcnt = 0u; tcnt = 0u; sCntLt = 0u; sFtb = FNB; }
  __syncthreads();                                         // 1
  float cmax;
  { float m = fredw[0];
#pragma unroll
    for (int j = 1; j < 16; ++j) m = fmaxf(m, fredw[j]);
    cmax = m; }

  // ---- coarse slab sum (4-way split, 16 coalesced u16 loads/thread) ----
  {
    int bk = tid & 255, cq = tid >> 8;
    unsigned part = 0;
#pragma unroll
    for (int t2 = 0; t2 < 16; ++t2)
      part += (unsigned)histg[((size_t)(cq * 16 + t2) * B + b) * NBK + bk];
    sp[tid] = part;
  }
  __syncthreads();                                         // 2
  {
    unsigned v = 0;
    if (tid < 256) {
      v = sp[tid] + sp[tid + 256] + sp[tid + 512] + sp[tid + 768];
#pragma unroll
      for (int off = 1; off < 64; off <<= 1) {             // wave inclusive scan
        unsigned t = (unsigned)__shfl_up((int)v, off, 64);
        if (lane >= off) v += t;
      }
      if (lane == 63) wtot[wid] = v;
    }
    __syncthreads();                                       // 3
    if (tid < 256) {
      for (int j = 0; j < wid; ++j) v += wtot[j];
      s[tid] = v;                                          // inclusive cumulative
    }
  }
  __syncthreads();                                         // 4
  unsigned K = (unsigned)Kp[0];
  if (tid < 256) {
    unsigned prev = tid ? s[tid - 1] : 0u;
    if (s[tid] >= K && prev < K) sTb = tid;                // exactly one thread
  }
  __syncthreads();                                         // 5
  int tb = sTb;
  double lo, inv, bwd;
  rowRange(B1sq[b], (double)cmax, lo, inv, bwd);
  double S = sqrt(B1sq[b] * (double)cmax);
  double Mtot = 2.0 * (0.5 * S * 1.1e-3 + 0.05) + 1e-3;    // 2M + abs slack
  int q = (int)ceil(Mtot / bwd);
  int belowMax = tb - 1 - q;                               // certainly in top-K
  int candMax = tb + 1 + q;                                // candidate window
  if (candMax > NBK - 1) candMax = NBK - 1;
  unsigned btot = (belowMax >= 0) ? s[belowMax] : 0u;
  int shift = *shiftp;

  // ---- classify stream: 2-deep MLP grid-stride uint4 ----
  {
    const uint4* bw16 = (const uint4*)(buck + (size_t)b * N);
    int nw16 = N >> 4;
#define CLS1(nn, bkv)                                                  \
    { int bk_ = (int)(bkv);                                            \
      if (bk_ <= belowMax) {                                           \
        unsigned p_ = atomicAdd(&bcnt, 1u);                            \
        if (p_ < BCAP) blist[p_] = (nn);                               \
      } else if (bk_ <= candMax) {                                     \
        unsigned p_ = atomicAdd(&ccnt, 1u);                            \
        if (p_ < CAPC) kidx[p_] = (nn);                                \
      } }
#define PROCV(vv, nb)                                                  \
    { unsigned w_;                                                     \
      w_ = (vv).x; CLS1((nb)+0,  w_ & 0xFF) CLS1((nb)+1,  (w_>>8)&0xFF)\
                   CLS1((nb)+2,  (w_>>16)&0xFF) CLS1((nb)+3,  w_>>24)  \
      w_ = (vv).y; CLS1((nb)+4,  w_ & 0xFF) CLS1((nb)+5,  (w_>>8)&0xFF)\
                   CLS1((nb)+6,  (w_>>16)&0xFF) CLS1((nb)+7,  w_>>24)  \
      w_ = (vv).z; CLS1((nb)+8,  w_ & 0xFF) CLS1((nb)+9,  (w_>>8)&0xFF)\
                   CLS1((nb)+10, (w_>>16)&0xFF) CLS1((nb)+11, w_>>24)  \
      w_ = (vv).w; CLS1((nb)+12, w_ & 0xFF) CLS1((nb)+13, (w_>>8)&0xFF)\
                   CLS1((nb)+14, (w_>>16)&0xFF) CLS1((nb)+15, w_>>24) }
    for (int i = tid; i < nw16; i += 2048) {
      uint4 v0 = bw16[i];
      int i1 = i + 1024; bool h1 = i1 < nw16;
      uint4 v1 = {0u, 0u, 0u, 0u};
      if (h1) v1 = bw16[i1];
      PROCV(v0, i << 4)
      if (h1) PROCV(v1, i1 << 4)
    }
#undef PROCV
    for (int n = (nw16 << 4) + tid; n < N; n += 1024) {    // tail
      CLS1(n, buck[(size_t)b * N + n])
    }
#undef CLS1
  }
  __syncthreads();                                         // 6

  // ---- below labels (exec-full) + candidate exact dots (independent) ----
  {
    int bm = (int)bcnt; if (bm > BCAP) bm = BCAP;
    for (int i = tid; i < bm; i += 1024)
      atomicAdd(&lab[labels[(size_t)blist[i] << shift]], 1u);
  }
  int cc = (int)ccnt; if (cc > CAPC) cc = CAPC;
  {
    int g = tid >> 4, gl = tid & 15;                       // 64 groups x 16 lanes
    for (int i = g; i < cc; i += 64) {
      int n = kidx[i];
      float4 qv = ((const float4*)(codes + (size_t)n * 64))[gl];
      double p = fma((double)qv.x, sod[gl*4+0], 0.0);
      p = fma((double)qv.y, sod[gl*4+1], p);
      p = fma((double)qv.z, sod[gl*4+2], p);
      p = fma((double)qv.w, sod[gl*4+3], p);
      p += __shfl_xor(p, 1, 16);                           // deterministic butterfly
      p += __shfl_xor(p, 2, 16);
      p += __shfl_xor(p, 4, 16);
      p += __shfl_xor(p, 8, 16);
      if (gl == 0) key[i] = fma(p, -0.5, 50.0);
    }
  }
  __syncthreads();                                         // 7

  // ---- fine-bucket selection over exact keys (monotone map) ----
  int need = (int)K - (int)btot;                           // >= 1
  double fLo = lo + (double)(belowMax + 1) * bwd - Mtot;
  double fInv = (double)FNB / ((double)(candMax - belowMax) * bwd + 2.0 * Mtot);
  for (int i = tid; i < cc; i += 1024) {
    int fb = (int)((key[i] - fLo) * fInv);
    fb = fb < 0 ? 0 : (fb > FNB - 1 ? FNB - 1 : fb);
    atomicAdd(&fhist[fb], 1u);
  }
  __syncthreads();                                         // 8
  {
    unsigned v = fhist[tid];
#pragma unroll
    for (int off = 1; off < 64; off <<= 1) {
      unsigned t = (unsigned)__shfl_up((int)v, off, 64);
      if (lane >= off) v += t;
    }
    if (lane == 63) ftot[wid] = v;
    sp[tid] = v;                                           // wave-local inclusive
  }
  __syncthreads();                                         // 9
  {
    unsigned off = 0;
    for (int j = 0; j < wid; ++j) off += ftot[j];
    unsigned ci = sp[tid] + off;                           // inclusive cum
    unsigned ce = ci - fhist[tid];                         // exclusive cum
    if ((int)ci >= need && (int)ce < need) { sFtb = tid; sCntLt = ce; }
  }
  __syncthreads();                                         // 10
  int ftb = sFtb;
  // emit: certain candidates -> labels; threshold fine-bucket -> tlist
  for (int i = tid; i < cc; i += 1024) {
    int fb = (int)((key[i] - fLo) * fInv);
    fb = fb < 0 ? 0 : (fb > FNB - 1 ? FNB - 1 : fb);
    if (fb < ftb) {
      atomicAdd(&lab[labels[(size_t)kidx[i] << shift]], 1u);
    } else if (fb == ftb) {
      unsigned p_ = atomicAdd(&tcnt, 1u);
      if (p_ < CAPC) tlist[p_] = (unsigned short)i;
    }
  }
  __syncthreads();                                         // 11
  {
    int tn = (int)tcnt; if (tn > CAPC) tn = CAPC;
    int rem = need - (int)sCntLt;                          // in [1, fhist[ftb]]
    for (int j = tid; j < tn; j += 1024) {
      int i = (int)tlist[j];
      double ki = key[i]; int ii = kidx[i];
      int rank = 0;
      for (int j2 = 0; j2 < tn; ++j2) {
        int i2 = (int)tlist[j2];
        double k2 = key[i2];
        rank += (k2 < ki || (k2 == ki && kidx[i2] < ii)) ? 1 : 0;
      }
      if (rank < rem) atomicAdd(&lab[labels[(size_t)ii << shift]], 1u);
    }
  }
  __syncthreads();                                         // 12
  double Kd = (double)K;
  for (int c = tid; c < NCLS; c += 1024)
    outp[b * NCLS + c] = (float)((double)lab[c] / Kd);
}

extern "C" void kernel_launch(void* const* d_in, const int* in_sizes, int n_in,
                              void* d_out, int out_size, void* d_ws, size_t ws_size,
                              hipStream_t stream) {
  const float* x     = (const float*)d_in[0];
  const float* W     = (const float*)d_in[1];
  const float* codes = (const float*)d_in[2];
  const int* labels  = (const int*)d_in[3];
  const int* Kp      = (const int*)d_in[4];

  const int B = out_size / NCLS;             // 256
  const int N = in_sizes[3];                 // 100000
  const int D = in_sizes[0] / B;             // 2048
  const int Npad = (N + 255) & ~255;         // 100096
  const int cpb = (((N + NCHX - 1) / NCHX) + 63) & ~63;  // 1600 codes per chunk
  const int nCvt = Npad / 256;               // 391 cvtnorm blocks

  // ws layout; nothing needs host-side init (all state written before read).
  char* p = (char*)d_ws;
  double* out64      = (double*)p;   p += (size_t)B * 64 * sizeof(double);       // 128 KB
  unsigned short* out16 = (unsigned short*)p; p += (size_t)B * 64 * 2;           // 32 KB
  double* B1sq       = (double*)p;   p += (size_t)B * sizeof(double);            // 2 KB
  int* shiftp        = (int*)p;      p += 64;
  float* cmaxSlab    = (float*)p;    p += 4096;                                  // nCvt floats
  unsigned short* histg = (unsigned short*)p; p += (size_t)NCHX * B * NBK * 2;   // 8 MB
  unsigned char* buck   = (unsigned char*)p;  p += (size_t)B * N;                // 25.6 MB
  unsigned short* codes16 = (unsigned short*)p;                                  // 12.8 MB

  k_prep<<<nCvt + B + 1, 256, 0, stream>>>(x, W, codes, labels, N, Npad, D, B, nCvt,
                                           codes16, cmaxSlab, out64, out16, B1sq, shiftp);
  k_mhist<<<dim3(NCHX, B / MROWS), 256, 0, stream>>>(codes16, out16, B1sq, cmaxSlab,
                                                     nCvt, N, Npad, cpb, B, histg, buck);
  k_rowfinal<<<B, 1024, 0, stream>>>(codes, out64, B1sq, cmaxSlab, histg, buck,
                                     labels, shiftp, Kp, (float*)d_out, nCvt, N, B);
}

// Round 8
// 152.435 us; speedup vs baseline: 3.3592x; 1.0524x over previous
//
#include <hip/hip_runtime.h>
#include <hip/hip_fp16.h>

// B=256 queries, D=2048, d=64 hash dim, N=100000 database, C=100 classes,
// K=1000 SMALLEST-sim selection. Inputs f32, labels int, output f32.
//
// R14: R13 pipeline; k_prep rebuilt for MLP. R13 PMC: prep 44us moving 29MB
// at 650 GB/s with VGPR=44 — ~1.5 lines in flight/wave (latency-bound, not
// pattern-bound). Now 1024 thr/block: cvt = 4 hoisted float4 loads/thread
// (named regs, issued before use); matmul = LDS-staged x row + 16 w-groups
// (4x waves) + unroll-2 W loads; B1sq via deterministic shfl butterfly.
//   k_prep    : detect + codes f32->f16 (+max||c||^2 slab) + out=x@W f64/f16
//   k_mhist   : MFMA screen -> u8 bucket[B][N] + u16 hist slabs [NCHX][B][NBK]
//   k_rowfinal: per-row: slab-sum+scan -> tb -> stream buck -> below/cand ->
//               f64 group-dots -> fine-bucket select -> label hist -> probs
// No memset, no global atomics, no cooperative launch; poison-safe.

#define NBK 256          // coarse buckets per row histogram (pow2)
#define FNB 1024         // fine buckets for candidate selection (pow2)
#define CAPC 2048        // per-row candidate capacity (expected ~900)
#define BCAP 2048        // per-row below-list capacity (btot < K)
#define MROWS 32         // out-rows per MFMA block (two 16-row tiles)
#define NCHX 64          // code-chunks for MFMA pass
#define NCLS 100

typedef _Float16 half8 __attribute__((ext_vector_type(8)));
typedef float floatx4 __attribute__((ext_vector_type(4)));

static __device__ __forceinline__ unsigned packh2(float a, float b) {
  _Float16 ha = (_Float16)a, hb = (_Float16)b;      // RNE
  unsigned short ua, ub;
  __builtin_memcpy(&ua, &ha, 2); __builtin_memcpy(&ub, &hb, 2);
  return (unsigned)ua | ((unsigned)ub << 16);
}

// shared range math (1-ulp discrepancies absorbed by margins; M>=0.05)
static __device__ __forceinline__ void rowRange(double b1sq, double cmax,
                                                double& lo, double& inv, double& bw) {
  double hr = 0.5 * sqrt(b1sq * cmax) * 1.000001 + 9.0;  // +9 >> M
  lo = 50.0 - hr;
  bw = (2.0 * hr) / (double)NBK;
  inv = (double)NBK / (2.0 * hr);
}

// ---- MFMA A-fragment loader (mfma_f32_16x16x32_f16 layout, m89-verified):
//   A: lane holds A[m = lane&15][k = (lane>>4)*8 + j]; D: reg r = D[(lane>>4)*4+r][lane&15]
static __device__ __forceinline__ void loadA(const unsigned short* __restrict__ out16,
                                             int m0, int mr, int quad,
                                             half8& a00, half8& a01, half8& a10, half8& a11) {
  const uint4* o4 = (const uint4*)out16;
  uint4 u;
  u = o4[(size_t)(m0 + mr) * 8 + quad];          __builtin_memcpy(&a00, &u, 16);
  u = o4[(size_t)(m0 + mr) * 8 + 4 + quad];      __builtin_memcpy(&a01, &u, 16);
  u = o4[(size_t)(m0 + 16 + mr) * 8 + quad];     __builtin_memcpy(&a10, &u, 16);
  u = o4[(size_t)(m0 + 16 + mr) * 8 + 4 + quad]; __builtin_memcpy(&a11, &u, 16);
}

// deterministic max over the cvtnorm slab, 256-thread version (k_mhist)
static __device__ __forceinline__ float reduceCmax256(const float* __restrict__ slab,
                                                      int n, float* fred) {
  int tid = (int)threadIdx.x;
  float m = 0.0f;
  for (int i = tid; i < n; i += 256) m = fmaxf(m, slab[i]);
  fred[tid] = m; __syncthreads();
  for (int off = 128; off > 0; off >>= 1) {
    if (tid < off) fred[tid] = fmaxf(fred[tid], fred[tid + off]);
    __syncthreads();
  }
  float r = fred[0];
  __syncthreads();
  return r;
}

// ============ k_prep v3: 1024 thr; cvt 4-deep MLP; matmul 16 w-groups ============
__global__ __launch_bounds__(1024) void k_prep(const float* __restrict__ x,
                                               const float* __restrict__ W,
                                               const float* __restrict__ codes,
                                               const int* __restrict__ labels,
                                               int N, int Npad, int D, int B, int nCvt,
                                               unsigned short* __restrict__ codes16,
                                               float* __restrict__ cmaxSlab,
                                               double* __restrict__ out64,
                                               unsigned short* __restrict__ out16,
                                               double* __restrict__ B1sq,
                                               int* __restrict__ shiftp) {
  __shared__ double red[1024];   // 8 KB (matmul reduce)
  __shared__ float xs[2048];     // 8 KB (staged x row)
  __shared__ float fredw[16];
  __shared__ int flag;
  int blk = (int)blockIdx.x, tid = (int)threadIdx.x;
  int lane = tid & 63, wid = tid >> 6;
  if (blk < nCvt) {
    // 256 rows per block, 16 lanes/row, 4 passes; all 4 loads hoisted.
    int gl = tid & 15, g = tid >> 4;                // g in 0..63
    int base = blk * 256;
    int r0 = base + g, r1 = base + 64 + g, r2 = base + 128 + g, r3 = base + 192 + g;
    float4 q0 = {0.f,0.f,0.f,0.f}, q1 = q0, q2 = q0, q3 = q0;
    if (r0 < N) q0 = ((const float4*)(codes + (size_t)r0 * 64))[gl];
    if (r1 < N) q1 = ((const float4*)(codes + (size_t)r1 * 64))[gl];
    if (r2 < N) q2 = ((const float4*)(codes + (size_t)r2 * 64))[gl];
    if (r3 < N) q3 = ((const float4*)(codes + (size_t)r3 * 64))[gl];
    // rows r0..r3 < Npad always (blk < Npad/256): stores unconditional
    uint2 o0, o1, o2, o3;
    o0.x = packh2(q0.x, q0.y); o0.y = packh2(q0.z, q0.w);
    o1.x = packh2(q1.x, q1.y); o1.y = packh2(q1.z, q1.w);
    o2.x = packh2(q2.x, q2.y); o2.y = packh2(q2.z, q2.w);
    o3.x = packh2(q3.x, q3.y); o3.y = packh2(q3.z, q3.w);
    ((uint2*)(codes16 + (size_t)r0 * 64))[gl] = o0;
    ((uint2*)(codes16 + (size_t)r1 * 64))[gl] = o1;
    ((uint2*)(codes16 + (size_t)r2 * 64))[gl] = o2;
    ((uint2*)(codes16 + (size_t)r3 * 64))[gl] = o3;
    float bmax = 0.0f;
#define NRM(qv)                                                            \
    { double c2 = fma((double)(qv).x, (double)(qv).x, 0.0);                \
      c2 = fma((double)(qv).y, (double)(qv).y, c2);                        \
      c2 = fma((double)(qv).z, (double)(qv).z, c2);                        \
      c2 = fma((double)(qv).w, (double)(qv).w, c2);                        \
      c2 += __shfl_xor(c2, 1, 16); c2 += __shfl_xor(c2, 2, 16);            \
      c2 += __shfl_xor(c2, 4, 16); c2 += __shfl_xor(c2, 8, 16);            \
      bmax = fmaxf(bmax, (float)(c2 * 1.000001)); }
    NRM(q0) NRM(q1) NRM(q2) NRM(q3)
#undef NRM
#pragma unroll
    for (int off = 32; off > 0; off >>= 1) bmax = fmaxf(bmax, __shfl_xor(bmax, off, 64));
    if (lane == 0) fredw[wid] = bmax;
    __syncthreads();
    if (tid == 0) {
      float m = fredw[0];
#pragma unroll
      for (int j = 1; j < 16; ++j) m = fmaxf(m, fredw[j]);
      cmaxSlab[blk] = m;                            // plain store (no init needed)
    }
  } else if (blk < nCvt + B) {   // out = x @ W in f64 (+f16 copy), ||out_b||^2
    int b = blk - nCvt;
    // stage x row in LDS (coalesced float2)
    const float* xr = x + (size_t)b * D;
    for (int i = tid; i < (D >> 1); i += 1024)
      ((float2*)xs)[i] = ((const float2*)xr)[i];
    __syncthreads();
    int t = tid & 63, w = tid >> 6;    // w in 0..15
    int kc = D >> 4;                   // 128 for D=2048
    int k0 = w * kc;
    double a[8];
#pragma unroll
    for (int j = 0; j < 8; ++j) a[j] = 0.0;
#pragma unroll 2
    for (int k = k0; k < k0 + kc; k += 8) {
#pragma unroll
      for (int j = 0; j < 8; ++j)
        a[j] = fma((double)xs[k + j], (double)W[(size_t)(k + j) * 64 + t], a[j]);
    }
    red[tid] = ((a[0] + a[1]) + (a[2] + a[3])) + ((a[4] + a[5]) + (a[6] + a[7]));
    __syncthreads();
    if (w == 0) {                      // threads 0..63 = wave 0
      double o = 0.0;
#pragma unroll
      for (int j = 0; j < 16; ++j) o += red[t + 64 * j];
      out64[(size_t)b * 64 + t] = o;
      _Float16 h = (_Float16)(float)o;       // RNE
      unsigned short us; __builtin_memcpy(&us, &h, 2);
      out16[(size_t)b * 64 + t] = us;
      double sq = o * o;                     // deterministic butterfly sum
#pragma unroll
      for (int off = 1; off < 64; off <<= 1) sq += __shfl_xor(sq, off, 64);
      if (t == 0) B1sq[b] = sq;
    }
  } else {                       // labels layout: int64 pairs vs int32
    if (tid == 0) flag = 0;
    __syncthreads();
    int m = N < 256 ? N : 256;
    if (tid < m && labels[2 * tid + 1] != 0) atomicOr(&flag, 1);
    __syncthreads();
    if (tid == 0) *shiftp = flag ? 0 : 1;    // label(n)=labels[n<<shift]
  }
}

// ============ k_mhist: MFMA screen -> u8 bucket array + u16 hist slabs ============
__global__ __launch_bounds__(256) void k_mhist(const unsigned short* __restrict__ codes16,
                                               const unsigned short* __restrict__ out16,
                                               const double* __restrict__ B1sq,
                                               const float* __restrict__ cmaxSlab,
                                               int nCvt, int N, int Npad, int cpb, int B,
                                               unsigned short* __restrict__ histg,
                                               unsigned char* __restrict__ buck) {
  __shared__ unsigned hist[MROWS * NBK];   // 32 KB
  __shared__ float sP[MROWS], sQ[MROWS], fred[256];
  int tid = (int)threadIdx.x;
  int m0 = (int)blockIdx.y * MROWS, cx = (int)blockIdx.x;
  float cmax = reduceCmax256(cmaxSlab, nCvt, fred);
  for (int i = tid; i < MROWS * NBK; i += 256) hist[i] = 0u;
  if (tid < MROWS) {
    double lo, inv, bw;
    rowRange(B1sq[m0 + tid], (double)cmax, lo, inv, bw);
    sP[tid] = (float)(-0.5 * inv);         // bucket = trunc(d*P + Q), monotone in v
    sQ[tid] = (float)((50.0 - lo) * inv);
  }
  __syncthreads();
  int l = tid & 63, w = tid >> 6;
  int quad = l >> 4, mr = l & 15;
  half8 a00, a01, a10, a11;
  loadA(out16, m0, mr, quad, a00, a01, a10, a11);
  float P0[4], Q0[4], P1[4], Q1[4];
#pragma unroll
  for (int r = 0; r < 4; ++r) {
    P0[r] = sP[quad*4 + r];      Q0[r] = sQ[quad*4 + r];
    P1[r] = sP[16 + quad*4 + r]; Q1[r] = sQ[16 + quad*4 + r];
  }
  int cstart = cx * cpb;
  int cend = cstart + cpb; if (cend > N) cend = N;
  const uint4* c4 = (const uint4*)codes16;
  floatx4 z = {0.f, 0.f, 0.f, 0.f};
  for (int base = cstart; base < cend; base += 64) {
    int nrow = base + w * 16 + mr;
    int nc = nrow < Npad ? nrow : Npad - 1;
    uint4 ub0 = c4[(size_t)nc * 8 + quad];
    uint4 ub1 = c4[(size_t)nc * 8 + 4 + quad];
    half8 b0, b1;
    __builtin_memcpy(&b0, &ub0, 16); __builtin_memcpy(&b1, &ub1, 16);
    floatx4 d0 = __builtin_amdgcn_mfma_f32_16x16x32_f16(a00, b0, z, 0, 0, 0);
    d0 = __builtin_amdgcn_mfma_f32_16x16x32_f16(a01, b1, d0, 0, 0, 0);
    floatx4 d1 = __builtin_amdgcn_mfma_f32_16x16x32_f16(a10, b0, z, 0, 0, 0);
    d1 = __builtin_amdgcn_mfma_f32_16x16x32_f16(a11, b1, d1, 0, 0, 0);
    if (nrow < N) {
#pragma unroll
      for (int r = 0; r < 4; ++r) {
        int bk0 = (int)fmaf(d0[r], P0[r], Q0[r]);
        bk0 = bk0 < 0 ? 0 : (bk0 > NBK-1 ? NBK-1 : bk0);
        atomicAdd(&hist[(quad*4 + r) * NBK + bk0], 1u);   // LDS: local, fast
        buck[(size_t)(m0 + quad*4 + r) * N + nrow] = (unsigned char)bk0;
        int bk1 = (int)fmaf(d1[r], P1[r], Q1[r]);
        bk1 = bk1 < 0 ? 0 : (bk1 > NBK-1 ? NBK-1 : bk1);
        atomicAdd(&hist[(16 + quad*4 + r) * NBK + bk1], 1u);
        buck[(size_t)(m0 + 16 + quad*4 + r) * N + nrow] = (unsigned char)bk1;
      }
    }
  }
  __syncthreads();
  // exclusive slab, plain coalesced u16 stores (counts <= cpb=1600 < 65535)
  for (int i = tid; i < MROWS * NBK; i += 256)
    histg[((size_t)cx * B + (m0 + (i >> 8))) * NBK + (i & (NBK - 1))] =
        (unsigned short)hist[i];
}

// ============ k_rowfinal: one 1024-thr block per row, ~12 barriers ============
__global__ __launch_bounds__(1024) void k_rowfinal(const float* __restrict__ codes,
                                                   const double* __restrict__ out64,
                                                   const double* __restrict__ B1sq,
                                                   const float* __restrict__ cmaxSlab,
                                                   const unsigned short* __restrict__ histg,
                                                   const unsigned char* __restrict__ buck,
                                                   const int* __restrict__ labels,
                                                   const int* __restrict__ shiftp,
                                                   const int* __restrict__ Kp,
                                                   float* __restrict__ outp,
                                                   int nCvt, int N, int B) {
  __shared__ float fredw[16];
  __shared__ unsigned sp[1024];            // slab partials; reused for fine scan
  __shared__ unsigned s[NBK];              // coarse cumulative hist
  __shared__ unsigned wtot[4];
  __shared__ double key[CAPC];             // 16 KB
  __shared__ int kidx[CAPC];               // 8 KB
  __shared__ int blist[BCAP];              // 8 KB
  __shared__ unsigned fhist[FNB];          // 4 KB
  __shared__ unsigned ftot[16];
  __shared__ unsigned short tlist[CAPC];   // 4 KB (indices into key/kidx)
  __shared__ double sod[64];
  __shared__ unsigned lab[NCLS];
  __shared__ unsigned ccnt, bcnt, tcnt, sCntLt;
  __shared__ int sTb, sFtb;
  int b = (int)blockIdx.x, tid = (int)threadIdx.x;
  int lane = tid & 63, wid = tid >> 6;

  // ---- init + cmax wave-reduce (order-independent exact max) ----
  {
    float m = (tid < nCvt) ? cmaxSlab[tid] : 0.0f;
    for (int i = tid + 1024; i < nCvt; i += 1024) m = fmaxf(m, cmaxSlab[i]);
#pragma unroll
    for (int off = 32; off > 0; off >>= 1) m = fmaxf(m, __shfl_xor(m, off, 64));
    if (lane == 0) fredw[wid] = m;
  }
  fhist[tid] = 0u;
  if (tid < 64) sod[tid] = out64[(size_t)b * 64 + tid];
  if (tid < NCLS) lab[tid] = 0u;
  if (tid == 0) { ccnt = 0u; bcnt = 0u; tcnt = 0u; sCntLt = 0u; sFtb = FNB; }
  __syncthreads();                                         // 1
  float cmax;
  { float m = fredw[0];
#pragma unroll
    for (int j = 1; j < 16; ++j) m = fmaxf(m, fredw[j]);
    cmax = m; }

  // ---- coarse slab sum (4-way split, 16 coalesced u16 loads/thread) ----
  {
    int bk = tid & 255, cq = tid >> 8;
    unsigned part = 0;
#pragma unroll
    for (int t2 = 0; t2 < 16; ++t2)
      part += (unsigned)histg[((size_t)(cq * 16 + t2) * B + b) * NBK + bk];
    sp[tid] = part;
  }
  __syncthreads();                                         // 2
  {
    unsigned v = 0;
    if (tid < 256) {
      v = sp[tid] + sp[tid + 256] + sp[tid + 512] + sp[tid + 768];
#pragma unroll
      for (int off = 1; off < 64; off <<= 1) {             // wave inclusive scan
        unsigned t = (unsigned)__shfl_up((int)v, off, 64);
        if (lane >= off) v += t;
      }
      if (lane == 63) wtot[wid] = v;
    }
    __syncthreads();                                       // 3
    if (tid < 256) {
      for (int j = 0; j < wid; ++j) v += wtot[j];
      s[tid] = v;                                          // inclusive cumulative
    }
  }
  __syncthreads();                                         // 4
  unsigned K = (unsigned)Kp[0];
  if (tid < 256) {
    unsigned prev = tid ? s[tid - 1] : 0u;
    if (s[tid] >= K && prev < K) sTb = tid;                // exactly one thread
  }
  __syncthreads();                                         // 5
  int tb = sTb;
  double lo, inv, bwd;
  rowRange(B1sq[b], (double)cmax, lo, inv, bwd);
  double S = sqrt(B1sq[b] * (double)cmax);
  double Mtot = 2.0 * (0.5 * S * 1.1e-3 + 0.05) + 1e-3;    // 2M + abs slack
  int q = (int)ceil(Mtot / bwd);
  int belowMax = tb - 1 - q;                               // certainly in top-K
  int candMax = tb + 1 + q;                                // candidate window
  if (candMax > NBK - 1) candMax = NBK - 1;
  unsigned btot = (belowMax >= 0) ? s[belowMax] : 0u;
  int shift = *shiftp;

  // ---- classify stream: 2-deep MLP grid-stride uint4 ----
  {
    const uint4* bw16 = (const uint4*)(buck + (size_t)b * N);
    int nw16 = N >> 4;
#define CLS1(nn, bkv)                                                  \
    { int bk_ = (int)(bkv);                                            \
      if (bk_ <= belowMax) {                                           \
        unsigned p_ = atomicAdd(&bcnt, 1u);                            \
        if (p_ < BCAP) blist[p_] = (nn);                               \
      } else if (bk_ <= candMax) {                                     \
        unsigned p_ = atomicAdd(&ccnt, 1u);                            \
        if (p_ < CAPC) kidx[p_] = (nn);                                \
      } }
#define PROCV(vv, nb)                                                  \
    { unsigned w_;                                                     \
      w_ = (vv).x; CLS1((nb)+0,  w_ & 0xFF) CLS1((nb)+1,  (w_>>8)&0xFF)\
                   CLS1((nb)+2,  (w_>>16)&0xFF) CLS1((nb)+3,  w_>>24)  \
      w_ = (vv).y; CLS1((nb)+4,  w_ & 0xFF) CLS1((nb)+5,  (w_>>8)&0xFF)\
                   CLS1((nb)+6,  (w_>>16)&0xFF) CLS1((nb)+7,  w_>>24)  \
      w_ = (vv).z; CLS1((nb)+8,  w_ & 0xFF) CLS1((nb)+9,  (w_>>8)&0xFF)\
                   CLS1((nb)+10, (w_>>16)&0xFF) CLS1((nb)+11, w_>>24)  \
      w_ = (vv).w; CLS1((nb)+12, w_ & 0xFF) CLS1((nb)+13, (w_>>8)&0xFF)\
                   CLS1((nb)+14, (w_>>16)&0xFF) CLS1((nb)+15, w_>>24) }
    for (int i = tid; i < nw16; i += 2048) {
      uint4 v0 = bw16[i];
      int i1 = i + 1024; bool h1 = i1 < nw16;
      uint4 v1 = {0u, 0u, 0u, 0u};
      if (h1) v1 = bw16[i1];
      PROCV(v0, i << 4)
      if (h1) PROCV(v1, i1 << 4)
    }
#undef PROCV
    for (int n = (nw16 << 4) + tid; n < N; n += 1024) {    // tail
      CLS1(n, buck[(size_t)b * N + n])
    }
#undef CLS1
  }
  __syncthreads();                                         // 6

  // ---- below labels (exec-full) + candidate exact dots (independent) ----
  {
    int bm = (int)bcnt; if (bm > BCAP) bm = BCAP;
    for (int i = tid; i < bm; i += 1024)
      atomicAdd(&lab[labels[(size_t)blist[i] << shift]], 1u);
  }
  int cc = (int)ccnt; if (cc > CAPC) cc = CAPC;
  {
    int g = tid >> 4, gl = tid & 15;                       // 64 groups x 16 lanes
    for (int i = g; i < cc; i += 64) {
      int n = kidx[i];
      float4 qv = ((const float4*)(codes + (size_t)n * 64))[gl];
      double p = fma((double)qv.x, sod[gl*4+0], 0.0);
      p = fma((double)qv.y, sod[gl*4+1], p);
      p = fma((double)qv.z, sod[gl*4+2], p);
      p = fma((double)qv.w, sod[gl*4+3], p);
      p += __shfl_xor(p, 1, 16);                           // deterministic butterfly
      p += __shfl_xor(p, 2, 16);
      p += __shfl_xor(p, 4, 16);
      p += __shfl_xor(p, 8, 16);
      if (gl == 0) key[i] = fma(p, -0.5, 50.0);
    }
  }
  __syncthreads();                                         // 7

  // ---- fine-bucket selection over exact keys (monotone map) ----
  int need = (int)K - (int)btot;                           // >= 1
  double fLo = lo + (double)(belowMax + 1) * bwd - Mtot;
  double fInv = (double)FNB / ((double)(candMax - belowMax) * bwd + 2.0 * Mtot);
  for (int i = tid; i < cc; i += 1024) {
    int fb = (int)((key[i] - fLo) * fInv);
    fb = fb < 0 ? 0 : (fb > FNB - 1 ? FNB - 1 : fb);
    atomicAdd(&fhist[fb], 1u);
  }
  __syncthreads();                                         // 8
  {
    unsigned v = fhist[tid];
#pragma unroll
    for (int off = 1; off < 64; off <<= 1) {
      unsigned t = (unsigned)__shfl_up((int)v, off, 64);
      if (lane >= off) v += t;
    }
    if (lane == 63) ftot[wid] = v;
    sp[tid] = v;                                           // wave-local inclusive
  }
  __syncthreads();                                         // 9
  {
    unsigned off = 0;
    for (int j = 0; j < wid; ++j) off += ftot[j];
    unsigned ci = sp[tid] + off;                           // inclusive cum
    unsigned ce = ci - fhist[tid];                         // exclusive cum
    if ((int)ci >= need && (int)ce < need) { sFtb = tid; sCntLt = ce; }
  }
  __syncthreads();                                         // 10
  int ftb = sFtb;
  // emit: certain candidates -> labels; threshold fine-bucket -> tlist
  for (int i = tid; i < cc; i += 1024) {
    int fb = (int)((key[i] - fLo) * fInv);
    fb = fb < 0 ? 0 : (fb > FNB - 1 ? FNB - 1 : fb);
    if (fb < ftb) {
      atomicAdd(&lab[labels[(size_t)kidx[i] << shift]], 1u);
    } else if (fb == ftb) {
      unsigned p_ = atomicAdd(&tcnt, 1u);
      if (p_ < CAPC) tlist[p_] = (unsigned short)i;
    }
  }
  __syncthreads();                                         // 11
  {
    int tn = (int)tcnt; if (tn > CAPC) tn = CAPC;
    int rem = need - (int)sCntLt;                          // in [1, fhist[ftb]]
    for (int j = tid; j < tn; j += 1024) {
      int i = (int)tlist[j];
      double ki = key[i]; int ii = kidx[i];
      int rank = 0;
      for (int j2 = 0; j2 < tn; ++j2) {
        int i2 = (int)tlist[j2];
        double k2 = key[i2];
        rank += (k2 < ki || (k2 == ki && kidx[i2] < ii)) ? 1 : 0;
      }
      if (rank < rem) atomicAdd(&lab[labels[(size_t)ii << shift]], 1u);
    }
  }
  __syncthreads();                                         // 12
  double Kd = (double)K;
  for (int c = tid; c < NCLS; c += 1024)
    outp[b * NCLS + c] = (float)((double)lab[c] / Kd);
}

extern "C" void kernel_launch(void* const* d_in, const int* in_sizes, int n_in,
                              void* d_out, int out_size, void* d_ws, size_t ws_size,
                              hipStream_t stream) {
  const float* x     = (const float*)d_in[0];
  const float* W     = (const float*)d_in[1];
  const float* codes = (const float*)d_in[2];
  const int* labels  = (const int*)d_in[3];
  const int* Kp      = (const int*)d_in[4];

  const int B = out_size / NCLS;             // 256
  const int N = in_sizes[3];                 // 100000
  const int D = in_sizes[0] / B;             // 2048
  const int Npad = (N + 255) & ~255;         // 100096
  const int cpb = (((N + NCHX - 1) / NCHX) + 63) & ~63;  // 1600 codes per chunk
  const int nCvt = Npad / 256;               // 391 cvt blocks (256 rows each)

  // ws layout; nothing needs host-side init (all state written before read).
  char* p = (char*)d_ws;
  double* out64      = (double*)p;   p += (size_t)B * 64 * sizeof(double);       // 128 KB
  unsigned short* out16 = (unsigned short*)p; p += (size_t)B * 64 * 2;           // 32 KB
  double* B1sq       = (double*)p;   p += (size_t)B * sizeof(double);            // 2 KB
  int* shiftp        = (int*)p;      p += 64;
  float* cmaxSlab    = (float*)p;    p += 4096;                                  // nCvt floats
  unsigned short* histg = (unsigned short*)p; p += (size_t)NCHX * B * NBK * 2;   // 8 MB
  unsigned char* buck   = (unsigned char*)p;  p += (size_t)B * N;                // 25.6 MB
  unsigned short* codes16 = (unsigned short*)p;                                  // 12.8 MB

  k_prep<<<nCvt + B + 1, 1024, 0, stream>>>(x, W, codes, labels, N, Npad, D, B, nCvt,
                                            codes16, cmaxSlab, out64, out16, B1sq, shiftp);
  k_mhist<<<dim3(NCHX, B / MROWS), 256, 0, stream>>>(codes16, out16, B1sq, cmaxSlab,
                                                     nCvt, N, Npad, cpb, B, histg, buck);
  k_rowfinal<<<B, 1024, 0, stream>>>(codes, out64, B1sq, cmaxSlab, histg, buck,
                                     labels, shiftp, Kp, (float*)d_out, nCvt, N, B);
}